// Round 1
// baseline (2893.028 us; speedup 1.0000x reference)
//
#include <hip/hip_runtime.h>
#include <math.h>

#define B_ 16
#define S_ 2048
#define H_ 12
#define D_ 64
#define HID 768
#define A_ 40
#define SCALE_ 0.125f

// ---------------- QKV projection GEMM (fp32, LDS-tiled 64x64, 4x4/thread) ----------------
// C[m,n] = X[m,:] @ W[:,n] + bias[n];  m=(b,s), n=(h,d). K output pre-scaled by SCALE.
__global__ __launch_bounds__(256) void qkv_gemm(
    const float* __restrict__ X,
    const float* __restrict__ Wq, const float* __restrict__ bq,
    const float* __restrict__ Wk, const float* __restrict__ bk,
    const float* __restrict__ Wv, const float* __restrict__ bv,
    float* __restrict__ Q, float* __restrict__ K, float* __restrict__ V)
{
    const int z = blockIdx.z;
    const float* __restrict__ W    = (z == 0) ? Wq : (z == 1) ? Wk : Wv;
    const float* __restrict__ bias = (z == 0) ? bq : (z == 1) ? bk : bv;
    float* __restrict__ Out        = (z == 0) ? Q  : (z == 1) ? K  : V;

    __shared__ float As[16][64 + 4];  // [k][m], stride 68 floats (16B-aligned rows, conflict-free)
    __shared__ float Bs[16][64 + 4];  // [k][n]

    const int t  = threadIdx.x;
    const int tx = t & 15, ty = t >> 4;
    const int m0 = blockIdx.x * 64;
    const int n0 = blockIdx.y * 64;

    float acc[4][4] = {};

    const int ar = t >> 2, ac4 = t & 3;   // A-tile: 64 rows x 4 float4 of k
    const int br = t >> 4, bc4 = t & 15;  // B-tile: 16 k-rows x 16 float4 of n

    for (int k0 = 0; k0 < HID; k0 += 16) {
        float4 av  = *(const float4*)&X[(size_t)(m0 + ar) * HID + k0 + ac4 * 4];
        float4 bv4 = *(const float4*)&W[(size_t)(k0 + br) * HID + n0 + bc4 * 4];
        As[ac4 * 4 + 0][ar] = av.x;
        As[ac4 * 4 + 1][ar] = av.y;
        As[ac4 * 4 + 2][ar] = av.z;
        As[ac4 * 4 + 3][ar] = av.w;
        *(float4*)&Bs[br][bc4 * 4] = bv4;
        __syncthreads();
#pragma unroll
        for (int kk = 0; kk < 16; kk++) {
            float4 a4 = *(const float4*)&As[kk][ty * 4];
            float4 b4 = *(const float4*)&Bs[kk][tx * 4];
            float am[4] = {a4.x, a4.y, a4.z, a4.w};
            float bn[4] = {b4.x, b4.y, b4.z, b4.w};
#pragma unroll
            for (int i = 0; i < 4; i++)
#pragma unroll
                for (int j = 0; j < 4; j++)
                    acc[i][j] = fmaf(am[i], bn[j], acc[i][j]);
        }
        __syncthreads();
    }

    const int h = blockIdx.y;                  // 64-wide N tiles == one head each
    const float scl = (z == 1) ? SCALE_ : 1.0f;
    float4 bb = *(const float4*)&bias[n0 + tx * 4];
    float bj[4] = {bb.x, bb.y, bb.z, bb.w};
#pragma unroll
    for (int i = 0; i < 4; i++) {
        int m = m0 + ty * 4 + i;
        int b = m >> 11, s = m & 2047;
        size_t o = ((size_t)(b * H_ + h) * S_ + s) * D_ + tx * 4;
        float4 ov;
        ov.x = (acc[i][0] + bj[0]) * scl;
        ov.y = (acc[i][1] + bj[1]) * scl;
        ov.z = (acc[i][2] + bj[2]) * scl;
        ov.w = (acc[i][3] + bj[3]) * scl;
        *(float4*)&Out[o] = ov;
    }
}

// ---------------- agent pooling: 1D linear interp along seq (per b,h,d) ----------------
__global__ void agent_pool(const float* __restrict__ Q, float* __restrict__ Ag)
{
    int idx = blockIdx.x * 256 + threadIdx.x;
    if (idx >= B_ * H_ * A_ * D_) return;
    int d  = idx & 63;
    int a  = (idx >> 6) % A_;
    int bh = idx / (A_ * D_);
    float src = ((float)a + 0.5f) * (2048.0f / 40.0f) - 0.5f;
    src = fminf(fmaxf(src, 0.0f), 2047.0f);
    int lo = (int)floorf(src);
    int hi = min(lo + 1, S_ - 1);
    float w = src - (float)lo;
    const float* base = Q + (size_t)bh * (S_ * D_);
    Ag[idx] = base[lo * D_ + d] * (1.0f - w) + base[hi * D_ + d] * w;
}

// ---------------- stage 1: agent -> (K,V), online softmax over S ----------------
// score[a,s] = sum_d ag[a,d] * (Ksc[s,d] + dist[a-s+2047,d]) + mask[b,s]   (Ksc = SCALE*K)
__global__ __launch_bounds__(256) void stage1(
    const float* __restrict__ Kl, const float* __restrict__ Vl,
    const float* __restrict__ Ag, const float* __restrict__ dist,
    const float* __restrict__ mask, float* __restrict__ AgV)
{
    const int bh = blockIdx.x;
    const int b  = bh / H_;
    const float* __restrict__ kb = Kl + (size_t)bh * (S_ * D_);
    const float* __restrict__ vb = Vl + (size_t)bh * (S_ * D_);

    __shared__ float ag[A_][D_];
    __shared__ float kv[64][68];     // K tile, then reused as V tile
    __shared__ float sc[A_][68];     // scores -> probs
    __shared__ float accsh[A_][D_];
    __shared__ float mrow[A_], lrow[A_], resc[A_];

    const int t = threadIdx.x;
    for (int i = t; i < A_ * D_; i += 256) {
        ((float*)ag)[i]    = Ag[(size_t)bh * (A_ * D_) + i];
        ((float*)accsh)[i] = 0.0f;
    }
    if (t < A_) { mrow[t] = -INFINITY; lrow[t] = 0.0f; }
    __syncthreads();

    for (int s0 = 0; s0 < S_; s0 += 64) {
        // stage K tile (64 x 64 floats, float4, padded stride 68 keeps 16B alignment)
        for (int i = t; i < 1024; i += 256) {
            int r = i >> 4, c4 = i & 15;
            *(float4*)&kv[r][c4 * 4] = *(const float4*)&kb[(size_t)(s0 + r) * D_ + c4 * 4];
        }
        __syncthreads();
        // scores: 40x64 entries, 10 per thread
        for (int i = t; i < A_ * 64; i += 256) {
            int a = i >> 6, sl = i & 63;
            int srow = s0 + sl;
            const float* pe = dist + (size_t)(a - srow + 2047) * D_;
            float sum = 0.0f;
#pragma unroll
            for (int d4 = 0; d4 < 16; d4++) {
                float4 kk4 = *(const float4*)&kv[sl][d4 * 4];
                float4 pp  = *(const float4*)&pe[d4 * 4];
                float4 aa  = *(const float4*)&ag[a][d4 * 4];
                sum = fmaf(aa.x, kk4.x + pp.x, sum);
                sum = fmaf(aa.y, kk4.y + pp.y, sum);
                sum = fmaf(aa.z, kk4.z + pp.z, sum);
                sum = fmaf(aa.w, kk4.w + pp.w, sum);
            }
            sc[a][sl] = sum + mask[(size_t)b * S_ + srow];
        }
        __syncthreads();
        // stage V tile (overwrites kv) + per-row online softmax by threads 0..39
        for (int i = t; i < 1024; i += 256) {
            int r = i >> 4, c4 = i & 15;
            *(float4*)&kv[r][c4 * 4] = *(const float4*)&vb[(size_t)(s0 + r) * D_ + c4 * 4];
        }
        if (t < A_) {
            float mold = mrow[t];
            float mx = mold;
            for (int sl = 0; sl < 64; sl++) mx = fmaxf(mx, sc[t][sl]);
            float r_ = __expf(mold - mx);   // mold=-inf on first tile -> 0
            float sum = 0.0f;
            for (int sl = 0; sl < 64; sl++) {
                float p = __expf(sc[t][sl] - mx);
                sc[t][sl] = p;
                sum += p;
            }
            lrow[t] = lrow[t] * r_ + sum;
            mrow[t] = mx;
            resc[t] = r_;
        }
        __syncthreads();
        // acc[a,d] = acc[a,d]*resc[a] + sum_sl p[a,sl] * V[sl,d]   (float4 over d)
        for (int i = t; i < A_ * 16; i += 256) {
            int a = i >> 4, d4 = i & 15;
            float4 acc4 = *(float4*)&accsh[a][d4 * 4];
            float rs = resc[a];
            acc4.x *= rs; acc4.y *= rs; acc4.z *= rs; acc4.w *= rs;
            for (int sl = 0; sl < 64; sl++) {
                float p = sc[a][sl];
                float4 vv = *(const float4*)&kv[sl][d4 * 4];
                acc4.x = fmaf(p, vv.x, acc4.x);
                acc4.y = fmaf(p, vv.y, acc4.y);
                acc4.z = fmaf(p, vv.z, acc4.z);
                acc4.w = fmaf(p, vv.w, acc4.w);
            }
            *(float4*)&accsh[a][d4 * 4] = acc4;
        }
        __syncthreads();
    }
    for (int i = t; i < A_ * D_; i += 256) {
        int a = i >> 6;
        AgV[(size_t)bh * (A_ * D_) + i] = ((float*)accsh)[i] / lrow[a];
    }
}

// ---------------- stage 2: query -> agents, softmax over A=40, one s per thread ----------------
__global__ __launch_bounds__(256) void stage2(
    const float* __restrict__ Ql, const float* __restrict__ Ag,
    const float* __restrict__ AgV, const float* __restrict__ dist,
    float* __restrict__ Out)
{
    const int bx = blockIdx.x;
    const int bh = bx >> 3;
    const int b = bh / H_, h = bh % H_;
    const int s0 = (bx & 7) * 256;
    const int t = threadIdx.x;
    const int s = s0 + t;

    __shared__ float ag2[A_][D_];   // SCALE * agent
    __shared__ float av[A_][D_];
    __shared__ float scl[256][41];  // per-thread score row (stride 41 -> conflict-free)

    for (int i = t; i < A_ * D_; i += 256) {
        ((float*)ag2)[i] = Ag[(size_t)bh * (A_ * D_) + i] * SCALE_;
        ((float*)av)[i]  = AgV[(size_t)bh * (A_ * D_) + i];
    }
    __syncthreads();

    const float* __restrict__ qrow = Ql + ((size_t)bh * S_ + s) * D_;
    float4 fq[16];
#pragma unroll
    for (int d4 = 0; d4 < 16; d4++) fq[d4] = *(const float4*)&qrow[d4 * 4];

    // score2[s,a] = sum_d q[s,d] * (SCALE*agent[a,d] + dist[s-a+2047,d])
    for (int a = 0; a < A_; a++) {
        const float* pe = dist + (size_t)(s - a + 2047) * D_;
        float sum = 0.0f;
#pragma unroll
        for (int d4 = 0; d4 < 16; d4++) {
            float4 pp = *(const float4*)&pe[d4 * 4];
            float4 aa = *(const float4*)&ag2[a][d4 * 4];
            float4 qq = fq[d4];
            sum = fmaf(qq.x, aa.x + pp.x, sum);
            sum = fmaf(qq.y, aa.y + pp.y, sum);
            sum = fmaf(qq.z, aa.z + pp.z, sum);
            sum = fmaf(qq.w, aa.w + pp.w, sum);
        }
        scl[t][a] = sum;
    }
    // softmax over the 40 agents (q_mask is constant along this axis -> cancels)
    float mx = -INFINITY;
    for (int a = 0; a < A_; a++) mx = fmaxf(mx, scl[t][a]);
    float sum = 0.0f;
    for (int a = 0; a < A_; a++) {
        float p = __expf(scl[t][a] - mx);
        scl[t][a] = p;
        sum += p;
    }
    float inv = 1.0f / sum;

    float4 o[16];
#pragma unroll
    for (int d4 = 0; d4 < 16; d4++) o[d4] = make_float4(0.f, 0.f, 0.f, 0.f);
    for (int a = 0; a < A_; a++) {
        float p = scl[t][a] * inv;
#pragma unroll
        for (int d4 = 0; d4 < 16; d4++) {
            float4 vv = *(const float4*)&av[a][d4 * 4];
            o[d4].x = fmaf(p, vv.x, o[d4].x);
            o[d4].y = fmaf(p, vv.y, o[d4].y);
            o[d4].z = fmaf(p, vv.z, o[d4].z);
            o[d4].w = fmaf(p, vv.w, o[d4].w);
        }
    }
    float* orow = Out + ((size_t)b * S_ + s) * HID + h * D_;
#pragma unroll
    for (int d4 = 0; d4 < 16; d4++) *(float4*)&orow[d4 * 4] = o[d4];
}

extern "C" void kernel_launch(void* const* d_in, const int* in_sizes, int n_in,
                              void* d_out, int out_size, void* d_ws, size_t ws_size,
                              hipStream_t stream) {
    const float* hs   = (const float*)d_in[0];
    const float* mask = (const float*)d_in[1];
    const float* Wq   = (const float*)d_in[2];
    const float* bq   = (const float*)d_in[3];
    const float* Wk   = (const float*)d_in[4];
    const float* bk   = (const float*)d_in[5];
    const float* Wv   = (const float*)d_in[6];
    const float* bv   = (const float*)d_in[7];
    const float* dist = (const float*)d_in[8];
    float* out = (float*)d_out;

    float* ws = (float*)d_ws;
    const size_t QKV = (size_t)B_ * H_ * S_ * D_;   // 25,165,824 floats each
    float* Q     = ws;
    float* K     = ws + QKV;
    float* V     = ws + 2 * QKV;
    float* Agent = ws + 3 * QKV;                    // B*H*A*D = 491,520 floats
    float* AgV   = Agent + (size_t)B_ * H_ * A_ * D_;
    // total ws: ~306 MB

    dim3 g1(S_ * B_ / 64, HID / 64, 3);             // (512, 12, 3)
    qkv_gemm<<<g1, 256, 0, stream>>>(hs, Wq, bq, Wk, bk, Wv, bv, Q, K, V);
    agent_pool<<<(B_ * H_ * A_ * D_ + 255) / 256, 256, 0, stream>>>(Q, Agent);
    stage1<<<B_ * H_, 256, 0, stream>>>(K, V, Agent, dist, mask, AgV);
    stage2<<<B_ * H_ * (S_ / 256), 256, 0, stream>>>(Q, Agent, AgV, dist, out);
}

// Round 2
// 1685.837 us; speedup vs baseline: 1.7161x; 1.7161x over previous
//
#include <hip/hip_runtime.h>
#include <math.h>

#define B_ 16
#define S_ 2048
#define H_ 12
#define D_ 64
#define HID 768
#define A_ 40
#define SCALE_ 0.125f

typedef __attribute__((ext_vector_type(8))) short short8v;   // 8 bf16 (4 VGPR)
typedef __attribute__((ext_vector_type(4))) float f32x4;     // MFMA C/D

__device__ __forceinline__ unsigned f2bf_bits(float x) {
    unsigned u = __float_as_uint(x);
    return (u + 0x7FFFu + ((u >> 16) & 1u)) >> 16;   // RTNE
}

// split 8 fp32 -> hi/lo bf16 packed as int4 (8 bf16 = 16B each)
__device__ __forceinline__ void split8(const float* x, int4& hi, int4& lo) {
    unsigned h[8], l[8];
#pragma unroll
    for (int i = 0; i < 8; i++) {
        unsigned hb = f2bf_bits(x[i]);
        float hf = __uint_as_float(hb << 16);
        unsigned lb = f2bf_bits(x[i] - hf);
        h[i] = hb; l[i] = lb;
    }
    hi = make_int4((int)(h[0] | (h[1] << 16)), (int)(h[2] | (h[3] << 16)),
                   (int)(h[4] | (h[5] << 16)), (int)(h[6] | (h[7] << 16)));
    lo = make_int4((int)(l[0] | (l[1] << 16)), (int)(l[2] | (l[3] << 16)),
                   (int)(l[4] | (l[5] << 16)), (int)(l[6] | (l[7] << 16)));
}

// ---------------- W transpose + bf16 hi/lo split: Wt[z][n][k] ----------------
__global__ void wt_convert(const float* __restrict__ Wq, const float* __restrict__ Wk,
                           const float* __restrict__ Wv,
                           unsigned short* __restrict__ Wth, unsigned short* __restrict__ Wtl)
{
    int idx = blockIdx.x * 256 + threadIdx.x;          // 3 * 192 * 768
    if (idx >= 3 * 192 * 768) return;
    int n  = idx % 768;
    int kc = (idx / 768) % 192;
    int z  = idx / (768 * 192);
    const float* W = (z == 0) ? Wq : (z == 1) ? Wk : Wv;
    unsigned short h4[4], l4[4];
#pragma unroll
    for (int i = 0; i < 4; i++) {
        float x = W[(size_t)(4 * kc + i) * HID + n];
        unsigned hb = f2bf_bits(x);
        float hf = __uint_as_float(hb << 16);
        h4[i] = (unsigned short)hb;
        l4[i] = (unsigned short)f2bf_bits(x - hf);
    }
    size_t o = ((size_t)z * HID + n) * HID + 4 * kc;
    *(ushort4*)&Wth[o] = make_ushort4(h4[0], h4[1], h4[2], h4[3]);
    *(ushort4*)&Wtl[o] = make_ushort4(l4[0], l4[1], l4[2], l4[3]);
}

// ---------------- QKV projection: bf16x3 MFMA GEMM, 128x128 tile, BK=32 ----------------
// C = X @ W + bias; X split hi/lo in-kernel; W pre-split. Out layout [b,h,s,d]; K pre-scaled.
__global__ __launch_bounds__(256, 2) void qkv_mfma(
    const float* __restrict__ X,
    const unsigned short* __restrict__ Wth, const unsigned short* __restrict__ Wtl,
    const float* __restrict__ bq, const float* __restrict__ bk, const float* __restrict__ bv,
    float* __restrict__ Q, float* __restrict__ K, float* __restrict__ V)
{
    const int nt = blockIdx.x;        // 0..5
    const int zz = blockIdx.y;        // 0..2
    const int mt = blockIdx.z;        // 0..255
    const int m0 = mt * 128, n0 = nt * 128;

    const float* __restrict__ bias = (zz == 0) ? bq : (zz == 1) ? bk : bv;
    float* __restrict__ Out        = (zz == 0) ? Q  : (zz == 1) ? K  : V;
    const unsigned short* __restrict__ Bhg = Wth + (size_t)zz * HID * HID;
    const unsigned short* __restrict__ Blg = Wtl + (size_t)zz * HID * HID;

    __shared__ unsigned short Ah[128][40];   // pad to 40 bf16 (80B rows, 16B-aligned, 2-way max)
    __shared__ unsigned short Al[128][40];
    __shared__ unsigned short Bh[128][40];
    __shared__ unsigned short Bl[128][40];

    const int t = threadIdx.x;
    const int lane = t & 63, w = t >> 6;
    const int wm = (w >> 1) * 64, wn = (w & 1) * 64;
    const int fr = lane & 15, kc = lane >> 4;

    const int sr = t >> 1, sc = (t & 1) * 16;   // staging: row, col-chunk(16 elems)

    f32x4 acc[4][4];
#pragma unroll
    for (int i = 0; i < 4; i++)
#pragma unroll
        for (int j = 0; j < 4; j++) acc[i][j] = (f32x4){0.f, 0.f, 0.f, 0.f};

    for (int k0 = 0; k0 < HID; k0 += 32) {
        // ---- stage: global -> reg (+convert A) ----
        float xv[16];
        const float* xp = X + (size_t)(m0 + sr) * HID + k0 + sc;
#pragma unroll
        for (int q = 0; q < 4; q++) {
            float4 f = *(const float4*)(xp + 4 * q);
            xv[4 * q + 0] = f.x; xv[4 * q + 1] = f.y; xv[4 * q + 2] = f.z; xv[4 * q + 3] = f.w;
        }
        int4 ah0, al0, ah1, al1;
        split8(xv, ah0, al0);
        split8(xv + 8, ah1, al1);
        size_t bo = (size_t)(n0 + sr) * HID + k0 + sc;
        int4 bh0 = *(const int4*)&Bhg[bo];
        int4 bh1 = *(const int4*)&Bhg[bo + 8];
        int4 bl0 = *(const int4*)&Blg[bo];
        int4 bl1 = *(const int4*)&Blg[bo + 8];

        __syncthreads();   // prior tile's reads complete
        *(int4*)&Ah[sr][sc]     = ah0;  *(int4*)&Ah[sr][sc + 8] = ah1;
        *(int4*)&Al[sr][sc]     = al0;  *(int4*)&Al[sr][sc + 8] = al1;
        *(int4*)&Bh[sr][sc]     = bh0;  *(int4*)&Bh[sr][sc + 8] = bh1;
        *(int4*)&Bl[sr][sc]     = bl0;  *(int4*)&Bl[sr][sc + 8] = bl1;
        __syncthreads();

        // ---- fragments + MFMA ----
        short8v a_h[4], a_l[4], b_h[4], b_l[4];
#pragma unroll
        for (int i = 0; i < 4; i++) {
            a_h[i] = *(const short8v*)&Ah[wm + i * 16 + fr][kc * 8];
            a_l[i] = *(const short8v*)&Al[wm + i * 16 + fr][kc * 8];
            b_h[i] = *(const short8v*)&Bh[wn + i * 16 + fr][kc * 8];
            b_l[i] = *(const short8v*)&Bl[wn + i * 16 + fr][kc * 8];
        }
#pragma unroll
        for (int i = 0; i < 4; i++)
#pragma unroll
            for (int j = 0; j < 4; j++) {
                acc[i][j] = __builtin_amdgcn_mfma_f32_16x16x32_bf16(a_h[i], b_h[j], acc[i][j], 0, 0, 0);
                acc[i][j] = __builtin_amdgcn_mfma_f32_16x16x32_bf16(a_l[i], b_h[j], acc[i][j], 0, 0, 0);
                acc[i][j] = __builtin_amdgcn_mfma_f32_16x16x32_bf16(a_h[i], b_l[j], acc[i][j], 0, 0, 0);
            }
    }

    // ---- epilogue: bias, optional SCALE (K), write [b,h,s,d] ----
    const float scl = (zz == 1) ? SCALE_ : 1.0f;
#pragma unroll
    for (int j = 0; j < 4; j++) {
        int n = n0 + wn + j * 16 + fr;
        float bj = bias[n];
        int h = n >> 6, d = n & 63;
#pragma unroll
        for (int i = 0; i < 4; i++) {
            int mb = m0 + wm + i * 16 + kc * 4;
#pragma unroll
            for (int r = 0; r < 4; r++) {
                int m = mb + r;
                int b = m >> 11, s = m & 2047;
                Out[(((size_t)b * H_ + h) * S_ + s) * D_ + d] = (acc[i][j][r] + bj) * scl;
            }
        }
    }
}

// ---------------- agent pooling: 1D linear interp along seq (per b,h,d) ----------------
__global__ void agent_pool(const float* __restrict__ Q, float* __restrict__ Ag)
{
    int idx = blockIdx.x * 256 + threadIdx.x;
    if (idx >= B_ * H_ * A_ * D_) return;
    int d  = idx & 63;
    int a  = (idx >> 6) % A_;
    int bh = idx / (A_ * D_);
    float src = ((float)a + 0.5f) * (2048.0f / 40.0f) - 0.5f;
    src = fminf(fmaxf(src, 0.0f), 2047.0f);
    int lo = (int)floorf(src);
    int hi = min(lo + 1, S_ - 1);
    float w = src - (float)lo;
    const float* base = Q + (size_t)bh * (S_ * D_);
    Ag[idx] = base[lo * D_ + d] * (1.0f - w) + base[hi * D_ + d] * w;
}

// ---------------- stage 1: agent -> (K,V), online softmax over S ----------------
__global__ __launch_bounds__(256) void stage1(
    const float* __restrict__ Kl, const float* __restrict__ Vl,
    const float* __restrict__ Ag, const float* __restrict__ dist,
    const float* __restrict__ mask, float* __restrict__ AgV)
{
    const int bh = blockIdx.x;
    const int b  = bh / H_;
    const float* __restrict__ kb = Kl + (size_t)bh * (S_ * D_);
    const float* __restrict__ vb = Vl + (size_t)bh * (S_ * D_);

    __shared__ float ag[A_][D_];
    __shared__ float kv[64][68];
    __shared__ float sc[A_][68];
    __shared__ float accsh[A_][D_];
    __shared__ float mrow[A_], lrow[A_], resc[A_];

    const int t = threadIdx.x;
    for (int i = t; i < A_ * D_; i += 256) {
        ((float*)ag)[i]    = Ag[(size_t)bh * (A_ * D_) + i];
        ((float*)accsh)[i] = 0.0f;
    }
    if (t < A_) { mrow[t] = -INFINITY; lrow[t] = 0.0f; }
    __syncthreads();

    for (int s0 = 0; s0 < S_; s0 += 64) {
        for (int i = t; i < 1024; i += 256) {
            int r = i >> 4, c4 = i & 15;
            *(float4*)&kv[r][c4 * 4] = *(const float4*)&kb[(size_t)(s0 + r) * D_ + c4 * 4];
        }
        __syncthreads();
        for (int i = t; i < A_ * 64; i += 256) {
            int a = i >> 6, sl = i & 63;
            int srow = s0 + sl;
            const float* pe = dist + (size_t)(a - srow + 2047) * D_;
            float sum = 0.0f;
#pragma unroll
            for (int d4 = 0; d4 < 16; d4++) {
                float4 kk4 = *(const float4*)&kv[sl][d4 * 4];
                float4 pp  = *(const float4*)&pe[d4 * 4];
                float4 aa  = *(const float4*)&ag[a][d4 * 4];
                sum = fmaf(aa.x, kk4.x + pp.x, sum);
                sum = fmaf(aa.y, kk4.y + pp.y, sum);
                sum = fmaf(aa.z, kk4.z + pp.z, sum);
                sum = fmaf(aa.w, kk4.w + pp.w, sum);
            }
            sc[a][sl] = sum + mask[(size_t)b * S_ + srow];
        }
        __syncthreads();
        for (int i = t; i < 1024; i += 256) {
            int r = i >> 4, c4 = i & 15;
            *(float4*)&kv[r][c4 * 4] = *(const float4*)&vb[(size_t)(s0 + r) * D_ + c4 * 4];
        }
        if (t < A_) {
            float mold = mrow[t];
            float mx = mold;
            for (int sl = 0; sl < 64; sl++) mx = fmaxf(mx, sc[t][sl]);
            float r_ = __expf(mold - mx);
            float sum = 0.0f;
            for (int sl = 0; sl < 64; sl++) {
                float p = __expf(sc[t][sl] - mx);
                sc[t][sl] = p;
                sum += p;
            }
            lrow[t] = lrow[t] * r_ + sum;
            mrow[t] = mx;
            resc[t] = r_;
        }
        __syncthreads();
        for (int i = t; i < A_ * 16; i += 256) {
            int a = i >> 4, d4 = i & 15;
            float4 acc4 = *(float4*)&accsh[a][d4 * 4];
            float rs = resc[a];
            acc4.x *= rs; acc4.y *= rs; acc4.z *= rs; acc4.w *= rs;
            for (int sl = 0; sl < 64; sl++) {
                float p = sc[a][sl];
                float4 vv = *(const float4*)&kv[sl][d4 * 4];
                acc4.x = fmaf(p, vv.x, acc4.x);
                acc4.y = fmaf(p, vv.y, acc4.y);
                acc4.z = fmaf(p, vv.z, acc4.z);
                acc4.w = fmaf(p, vv.w, acc4.w);
            }
            *(float4*)&accsh[a][d4 * 4] = acc4;
        }
        __syncthreads();
    }
    for (int i = t; i < A_ * D_; i += 256) {
        int a = i >> 6;
        AgV[(size_t)bh * (A_ * D_) + i] = ((float*)accsh)[i] / lrow[a];
    }
}

// ---------------- stage 2: query -> agents, softmax over A=40 ----------------
__global__ __launch_bounds__(256) void stage2(
    const float* __restrict__ Ql, const float* __restrict__ Ag,
    const float* __restrict__ AgV, const float* __restrict__ dist,
    float* __restrict__ Out)
{
    const int bx = blockIdx.x;
    const int bh = bx >> 3;
    const int b = bh / H_, h = bh % H_;
    const int s0 = (bx & 7) * 256;
    const int t = threadIdx.x;
    const int s = s0 + t;

    __shared__ float ag2[A_][D_];
    __shared__ float av[A_][D_];
    __shared__ float scl[256][41];

    for (int i = t; i < A_ * D_; i += 256) {
        ((float*)ag2)[i] = Ag[(size_t)bh * (A_ * D_) + i] * SCALE_;
        ((float*)av)[i]  = AgV[(size_t)bh * (A_ * D_) + i];
    }
    __syncthreads();

    const float* __restrict__ qrow = Ql + ((size_t)bh * S_ + s) * D_;
    float4 fq[16];
#pragma unroll
    for (int d4 = 0; d4 < 16; d4++) fq[d4] = *(const float4*)&qrow[d4 * 4];

    for (int a = 0; a < A_; a++) {
        const float* pe = dist + (size_t)(s - a + 2047) * D_;
        float sum = 0.0f;
#pragma unroll
        for (int d4 = 0; d4 < 16; d4++) {
            float4 pp = *(const float4*)&pe[d4 * 4];
            float4 aa = *(const float4*)&ag2[a][d4 * 4];
            float4 qq = fq[d4];
            sum = fmaf(qq.x, aa.x + pp.x, sum);
            sum = fmaf(qq.y, aa.y + pp.y, sum);
            sum = fmaf(qq.z, aa.z + pp.z, sum);
            sum = fmaf(qq.w, aa.w + pp.w, sum);
        }
        scl[t][a] = sum;
    }
    float mx = -INFINITY;
    for (int a = 0; a < A_; a++) mx = fmaxf(mx, scl[t][a]);
    float sum = 0.0f;
    for (int a = 0; a < A_; a++) {
        float p = __expf(scl[t][a] - mx);
        scl[t][a] = p;
        sum += p;
    }
    float inv = 1.0f / sum;

    float4 o[16];
#pragma unroll
    for (int d4 = 0; d4 < 16; d4++) o[d4] = make_float4(0.f, 0.f, 0.f, 0.f);
    for (int a = 0; a < A_; a++) {
        float p = scl[t][a] * inv;
#pragma unroll
        for (int d4 = 0; d4 < 16; d4++) {
            float4 vv = *(const float4*)&av[a][d4 * 4];
            o[d4].x = fmaf(p, vv.x, o[d4].x);
            o[d4].y = fmaf(p, vv.y, o[d4].y);
            o[d4].z = fmaf(p, vv.z, o[d4].z);
            o[d4].w = fmaf(p, vv.w, o[d4].w);
        }
    }
    float* orow = Out + ((size_t)b * S_ + s) * HID + h * D_;
#pragma unroll
    for (int d4 = 0; d4 < 16; d4++) *(float4*)&orow[d4 * 4] = o[d4];
}

extern "C" void kernel_launch(void* const* d_in, const int* in_sizes, int n_in,
                              void* d_out, int out_size, void* d_ws, size_t ws_size,
                              hipStream_t stream) {
    const float* hs   = (const float*)d_in[0];
    const float* mask = (const float*)d_in[1];
    const float* Wq   = (const float*)d_in[2];
    const float* bq   = (const float*)d_in[3];
    const float* Wk   = (const float*)d_in[4];
    const float* bk   = (const float*)d_in[5];
    const float* Wv   = (const float*)d_in[6];
    const float* bv   = (const float*)d_in[7];
    const float* dist = (const float*)d_in[8];
    float* out = (float*)d_out;

    float* ws = (float*)d_ws;
    const size_t QKV = (size_t)B_ * H_ * S_ * D_;   // 25,165,824 floats each
    const size_t AG  = (size_t)B_ * H_ * A_ * D_;   // 491,520 floats
    float* Q     = ws;
    float* K     = ws + QKV;
    float* V     = ws + 2 * QKV;
    float* Agent = ws + 3 * QKV;
    float* AgV   = Agent + AG;
    unsigned short* Wth = (unsigned short*)(AgV + AG);
    unsigned short* Wtl = Wth + (size_t)3 * HID * HID;
    // total ws: ~313 MB

    wt_convert<<<(3 * 192 * 768 + 255) / 256, 256, 0, stream>>>(Wq, Wk, Wv, Wth, Wtl);
    dim3 gg(6, 3, 256);
    qkv_mfma<<<gg, 256, 0, stream>>>(hs, Wth, Wtl, bq, bk, bv, Q, K, V);
    agent_pool<<<(B_ * H_ * A_ * D_ + 255) / 256, 256, 0, stream>>>(Q, Agent);
    stage1<<<B_ * H_, 256, 0, stream>>>(K, V, Agent, dist, mask, AgV);
    stage2<<<B_ * H_ * (S_ / 256), 256, 0, stream>>>(Q, Agent, AgV, dist, out);
}

// Round 3
// 1051.885 us; speedup vs baseline: 2.7503x; 1.6027x over previous
//
#include <hip/hip_runtime.h>
#include <math.h>

#define B_ 16
#define S_ 2048
#define H_ 12
#define D_ 64
#define HID 768
#define A_ 40
#define SCALE_ 0.125f
#define CH1 8          // stage1 s-chunks per (b,h)
#define SUBT 64        // s per subtile
#define NSUB 4         // subtiles per block (256 s per block)

typedef __attribute__((ext_vector_type(8))) short short8v;   // 8 bf16 (4 VGPR)
typedef __attribute__((ext_vector_type(4))) float f32x4;     // MFMA C/D

__device__ __forceinline__ unsigned f2bf_bits(float x) {
    unsigned u = __float_as_uint(x);
    return (u + 0x7FFFu + ((u >> 16) & 1u)) >> 16;   // RTNE
}

// split 8 fp32 -> hi/lo bf16 packed as int4 (8 bf16 = 16B each)
__device__ __forceinline__ void split8(const float* x, int4& hi, int4& lo) {
    unsigned h[8], l[8];
#pragma unroll
    for (int i = 0; i < 8; i++) {
        unsigned hb = f2bf_bits(x[i]);
        float hf = __uint_as_float(hb << 16);
        unsigned lb = f2bf_bits(x[i] - hf);
        h[i] = hb; l[i] = lb;
    }
    hi = make_int4((int)(h[0] | (h[1] << 16)), (int)(h[2] | (h[3] << 16)),
                   (int)(h[4] | (h[5] << 16)), (int)(h[6] | (h[7] << 16)));
    lo = make_int4((int)(l[0] | (l[1] << 16)), (int)(l[2] | (l[3] << 16)),
                   (int)(l[4] | (l[5] << 16)), (int)(l[6] | (l[7] << 16)));
}

// ---------------- W transpose + bf16 hi/lo split: Wt[z][n][k] ----------------
__global__ void wt_convert(const float* __restrict__ Wq, const float* __restrict__ Wk,
                           const float* __restrict__ Wv,
                           unsigned short* __restrict__ Wth, unsigned short* __restrict__ Wtl)
{
    int idx = blockIdx.x * 256 + threadIdx.x;          // 3 * 192 * 768
    if (idx >= 3 * 192 * 768) return;
    int n  = idx % 768;
    int kc = (idx / 768) % 192;
    int z  = idx / (768 * 192);
    const float* W = (z == 0) ? Wq : (z == 1) ? Wk : Wv;
    unsigned short h4[4], l4[4];
#pragma unroll
    for (int i = 0; i < 4; i++) {
        float x = W[(size_t)(4 * kc + i) * HID + n];
        unsigned hb = f2bf_bits(x);
        float hf = __uint_as_float(hb << 16);
        h4[i] = (unsigned short)hb;
        l4[i] = (unsigned short)f2bf_bits(x - hf);
    }
    size_t o = ((size_t)z * HID + n) * HID + 4 * kc;
    *(ushort4*)&Wth[o] = make_ushort4(h4[0], h4[1], h4[2], h4[3]);
    *(ushort4*)&Wtl[o] = make_ushort4(l4[0], l4[1], l4[2], l4[3]);
}

// ---------------- QKV projection: bf16x3 MFMA GEMM, 128x128 tile, BK=32 ----------------
__global__ __launch_bounds__(256, 2) void qkv_mfma(
    const float* __restrict__ X,
    const unsigned short* __restrict__ Wth, const unsigned short* __restrict__ Wtl,
    const float* __restrict__ bq, const float* __restrict__ bk, const float* __restrict__ bv,
    float* __restrict__ Q, float* __restrict__ K, float* __restrict__ V)
{
    const int nt = blockIdx.x;        // 0..5
    const int zz = blockIdx.y;        // 0..2
    const int mt = blockIdx.z;        // 0..255
    const int m0 = mt * 128, n0 = nt * 128;

    const float* __restrict__ bias = (zz == 0) ? bq : (zz == 1) ? bk : bv;
    float* __restrict__ Out        = (zz == 0) ? Q  : (zz == 1) ? K  : V;
    const unsigned short* __restrict__ Bhg = Wth + (size_t)zz * HID * HID;
    const unsigned short* __restrict__ Blg = Wtl + (size_t)zz * HID * HID;

    __shared__ unsigned short Ah[128][40];
    __shared__ unsigned short Al[128][40];
    __shared__ unsigned short Bh[128][40];
    __shared__ unsigned short Bl[128][40];

    const int t = threadIdx.x;
    const int lane = t & 63, w = t >> 6;
    const int wm = (w >> 1) * 64, wn = (w & 1) * 64;
    const int fr = lane & 15, kc = lane >> 4;

    const int sr = t >> 1, sc = (t & 1) * 16;

    f32x4 acc[4][4];
#pragma unroll
    for (int i = 0; i < 4; i++)
#pragma unroll
        for (int j = 0; j < 4; j++) acc[i][j] = (f32x4){0.f, 0.f, 0.f, 0.f};

    for (int k0 = 0; k0 < HID; k0 += 32) {
        float xv[16];
        const float* xp = X + (size_t)(m0 + sr) * HID + k0 + sc;
#pragma unroll
        for (int q = 0; q < 4; q++) {
            float4 f = *(const float4*)(xp + 4 * q);
            xv[4 * q + 0] = f.x; xv[4 * q + 1] = f.y; xv[4 * q + 2] = f.z; xv[4 * q + 3] = f.w;
        }
        int4 ah0, al0, ah1, al1;
        split8(xv, ah0, al0);
        split8(xv + 8, ah1, al1);
        size_t bo = (size_t)(n0 + sr) * HID + k0 + sc;
        int4 bh0 = *(const int4*)&Bhg[bo];
        int4 bh1 = *(const int4*)&Bhg[bo + 8];
        int4 bl0 = *(const int4*)&Blg[bo];
        int4 bl1 = *(const int4*)&Blg[bo + 8];

        __syncthreads();
        *(int4*)&Ah[sr][sc]     = ah0;  *(int4*)&Ah[sr][sc + 8] = ah1;
        *(int4*)&Al[sr][sc]     = al0;  *(int4*)&Al[sr][sc + 8] = al1;
        *(int4*)&Bh[sr][sc]     = bh0;  *(int4*)&Bh[sr][sc + 8] = bh1;
        *(int4*)&Bl[sr][sc]     = bl0;  *(int4*)&Bl[sr][sc + 8] = bl1;
        __syncthreads();

        short8v a_h[4], a_l[4], b_h[4], b_l[4];
#pragma unroll
        for (int i = 0; i < 4; i++) {
            a_h[i] = *(const short8v*)&Ah[wm + i * 16 + fr][kc * 8];
            a_l[i] = *(const short8v*)&Al[wm + i * 16 + fr][kc * 8];
            b_h[i] = *(const short8v*)&Bh[wn + i * 16 + fr][kc * 8];
            b_l[i] = *(const short8v*)&Bl[wn + i * 16 + fr][kc * 8];
        }
#pragma unroll
        for (int i = 0; i < 4; i++)
#pragma unroll
            for (int j = 0; j < 4; j++) {
                acc[i][j] = __builtin_amdgcn_mfma_f32_16x16x32_bf16(a_h[i], b_h[j], acc[i][j], 0, 0, 0);
                acc[i][j] = __builtin_amdgcn_mfma_f32_16x16x32_bf16(a_l[i], b_h[j], acc[i][j], 0, 0, 0);
                acc[i][j] = __builtin_amdgcn_mfma_f32_16x16x32_bf16(a_h[i], b_l[j], acc[i][j], 0, 0, 0);
            }
    }

    const float scl = (zz == 1) ? SCALE_ : 1.0f;
#pragma unroll
    for (int j = 0; j < 4; j++) {
        int n = n0 + wn + j * 16 + fr;
        float bj = bias[n];
        int h = n >> 6, d = n & 63;
#pragma unroll
        for (int i = 0; i < 4; i++) {
            int mb = m0 + wm + i * 16 + kc * 4;
#pragma unroll
            for (int r = 0; r < 4; r++) {
                int m = mb + r;
                int b = m >> 11, s = m & 2047;
                Out[(((size_t)b * H_ + h) * S_ + s) * D_ + d] = (acc[i][j][r] + bj) * scl;
            }
        }
    }
}

// ---------------- agent pooling ----------------
__global__ void agent_pool(const float* __restrict__ Q, float* __restrict__ Ag)
{
    int idx = blockIdx.x * 256 + threadIdx.x;
    if (idx >= B_ * H_ * A_ * D_) return;
    int d  = idx & 63;
    int a  = (idx >> 6) % A_;
    int bh = idx / (A_ * D_);
    float src = ((float)a + 0.5f) * (2048.0f / 40.0f) - 0.5f;
    src = fminf(fmaxf(src, 0.0f), 2047.0f);
    int lo = (int)floorf(src);
    int hi = min(lo + 1, S_ - 1);
    float w = src - (float)lo;
    const float* base = Q + (size_t)bh * (S_ * D_);
    Ag[idx] = base[lo * D_ + d] * (1.0f - w) + base[hi * D_ + d] * w;
}

// ---------------- stage 1 partial: split-S flash, 4 online subtiles of 64 ----------------
// block = (bh, chunk q of 256 s). Writes unnormalized acc + per-chunk (m, l).
__global__ __launch_bounds__(256, 3) void stage1_part(
    const float* __restrict__ Kl, const float* __restrict__ Vl,
    const float* __restrict__ Ag, const float* __restrict__ dist,
    const float* __restrict__ mask,
    float* __restrict__ Pacc, float* __restrict__ Pm, float* __restrict__ Pl)
{
    const int q  = blockIdx.x;       // 0..7
    const int bh = blockIdx.y;       // 0..191
    const int b  = bh / H_;
    const int s0 = q * (NSUB * SUBT);
    const float* __restrict__ kb = Kl + (size_t)bh * (S_ * D_);
    const float* __restrict__ vb = Vl + (size_t)bh * (S_ * D_);

    __shared__ float ag[A_][D_];          // 10.0 KB
    __shared__ float pv[103 * 68];        // pe band (103x68) / V tile (64x68) overlay, 27.4 KB
    __shared__ float sc[SUBT][44];        // scores -> probs, 11 KB
    __shared__ float pm6[6][A_];          // split-reduction partials
    __shared__ float mrow[A_], lrow[A_], resc[A_];

    const int t  = threadIdx.x;
    const int sl = t >> 2, dq = t & 3;    // 64 s-slots x 4 d-quarters

    for (int i = t; i < A_ * D_ / 4; i += 256)
        ((float4*)ag)[i] = ((const float4*)(Ag + (size_t)bh * (A_ * D_)))[i];
    if (t < A_) { mrow[t] = -INFINITY; lrow[t] = 0.0f; }

    float4 acc[3];
#pragma unroll
    for (int ii = 0; ii < 3; ii++) acc[ii] = make_float4(0.f, 0.f, 0.f, 0.f);

    for (int st = 0; st < NSUB; st++) {
        const int sb = s0 + st * SUBT;
        const int jbase = 1984 - sb;      // dist rows jbase .. jbase+102

        // ---- stage pe band: 103 rows x 16 float4 (stride 68: bank-group conflict-free) ----
        __syncthreads();                  // prior subtile's phase C done (no-op on st=0 wrt pv)
        for (int i = t; i < 103 * 16; i += 256) {
            int r = i >> 4, c = i & 15;
            *(float4*)&pv[r * 68 + c * 4] = *(const float4*)&dist[(size_t)(jbase + r) * D_ + c * 4];
        }
        // per-thread K slice: 16 floats of row s = sb + sl
        const int s = sb + sl;
        float4 kreg[4];
        const float* kp = kb + (size_t)s * D_ + dq * 16;
#pragma unroll
        for (int c = 0; c < 4; c++) kreg[c] = *(const float4*)(kp + 4 * c);
        float mval = mask[(size_t)b * S_ + s];
        __syncthreads();

        // ---- phase A: scores (each s computed by a 4-lane group, shfl-combined) ----
        for (int a = 0; a < A_; a++) {
            const float* per = &pv[(a + 63 - sl) * 68 + dq * 16];
            const float* agr = &ag[a][dq * 16];
            float sum = 0.0f;
#pragma unroll
            for (int c = 0; c < 4; c++) {
                float4 p4 = *(const float4*)(per + 4 * c);
                float4 a4 = *(const float4*)(agr + 4 * c);
                float4 k4 = kreg[c];
                sum = fmaf(a4.x, k4.x + p4.x, sum);
                sum = fmaf(a4.y, k4.y + p4.y, sum);
                sum = fmaf(a4.z, k4.z + p4.z, sum);
                sum = fmaf(a4.w, k4.w + p4.w, sum);
            }
            sum += __shfl_xor(sum, 1);
            sum += __shfl_xor(sum, 2);
            if (dq == 0) sc[sl][a] = sum + mval;
        }
        __syncthreads();

        // ---- stage V tile into pv (pe dead now) + split partial max ----
        for (int i = t; i < SUBT * 16; i += 256) {
            int r = i >> 4, c = i & 15;
            *(float4*)&pv[r * 68 + c * 4] = *(const float4*)&vb[(size_t)(sb + r) * D_ + c * 4];
        }
        if (t < 240) {
            int a = t % 40, r6 = t / 40;
            float mx = -INFINITY;
            for (int i = r6; i < SUBT; i += 6) mx = fmaxf(mx, sc[i][a]);
            pm6[r6][a] = mx;
        }
        __syncthreads();
        if (t < A_) {
            float lm = pm6[0][t];
#pragma unroll
            for (int r6 = 1; r6 < 6; r6++) lm = fmaxf(lm, pm6[r6][t]);
            float mnew = fmaxf(mrow[t], lm);
            resc[t] = __expf(mrow[t] - mnew);   // 0 on first subtile
            mrow[t] = mnew;
        }
        __syncthreads();
        // exp in place
        for (int i = t; i < SUBT * A_; i += 256) {
            int rr = i / 40, aa = i - rr * 40;
            sc[rr][aa] = __expf(sc[rr][aa] - mrow[aa]);
        }
        __syncthreads();
        if (t < 240) {
            int a = t % 40, r6 = t / 40;
            float sm = 0.0f;
            for (int i = r6; i < SUBT; i += 6) sm += sc[i][a];
            pm6[r6][a] = sm;
        }
        __syncthreads();
        if (t < A_) {
            float ls = pm6[0][t] + pm6[1][t] + pm6[2][t] + pm6[3][t] + pm6[4][t] + pm6[5][t];
            lrow[t] = lrow[t] * resc[t] + ls;
        }

        // ---- phase C: acc[a,d4] = acc*resc[a] + sum_s p * V ----
#pragma unroll
        for (int ii = 0; ii < 3; ii++) {
            int i = t + ii * 256;
            if (i < A_ * 16) {
                int a = i >> 4, d4 = i & 15;
                float rs = resc[a];
                float4 c4 = acc[ii];
                c4.x *= rs; c4.y *= rs; c4.z *= rs; c4.w *= rs;
                for (int rr = 0; rr < SUBT; rr++) {
                    float p = sc[rr][a];
                    float4 v4 = *(const float4*)&pv[rr * 68 + d4 * 4];
                    c4.x = fmaf(p, v4.x, c4.x);
                    c4.y = fmaf(p, v4.y, c4.y);
                    c4.z = fmaf(p, v4.z, c4.z);
                    c4.w = fmaf(p, v4.w, c4.w);
                }
                acc[ii] = c4;
            }
        }
    }
    // ---- write partials ----
    __syncthreads();
#pragma unroll
    for (int ii = 0; ii < 3; ii++) {
        int i = t + ii * 256;
        if (i < A_ * 16) {
            int a = i >> 4, d4 = i & 15;
            *(float4*)&Pacc[(((size_t)(bh * CH1 + q) * A_) + a) * D_ + d4 * 4] = acc[ii];
        }
    }
    if (t < A_) {
        Pm[(size_t)(bh * CH1 + q) * A_ + t] = mrow[t];
        Pl[(size_t)(bh * CH1 + q) * A_ + t] = lrow[t];
    }
}

// ---------------- stage 1 reduce: merge CH1 chunk partials ----------------
__global__ __launch_bounds__(256) void stage1_reduce(
    const float* __restrict__ Pacc, const float* __restrict__ Pm,
    const float* __restrict__ Pl, float* __restrict__ AgV)
{
    const int bh = blockIdx.x;
    const int t = threadIdx.x;
    __shared__ float F[CH1][A_], Linv[A_];
    if (t < A_) {
        float M = -INFINITY;
#pragma unroll
        for (int q = 0; q < CH1; q++) M = fmaxf(M, Pm[(size_t)(bh * CH1 + q) * A_ + t]);
        float L = 0.0f;
#pragma unroll
        for (int q = 0; q < CH1; q++) {
            float f = __expf(Pm[(size_t)(bh * CH1 + q) * A_ + t] - M);
            F[q][t] = f;
            L = fmaf(f, Pl[(size_t)(bh * CH1 + q) * A_ + t], L);
        }
        Linv[t] = 1.0f / L;
    }
    __syncthreads();
#pragma unroll
    for (int ii = 0; ii < 3; ii++) {
        int i = t + ii * 256;
        if (i < A_ * 16) {
            int a = i >> 4, d4 = i & 15;
            float4 s4 = make_float4(0.f, 0.f, 0.f, 0.f);
            for (int q = 0; q < CH1; q++) {
                float f = F[q][a];
                float4 p4 = *(const float4*)&Pacc[(((size_t)(bh * CH1 + q) * A_) + a) * D_ + d4 * 4];
                s4.x = fmaf(f, p4.x, s4.x);
                s4.y = fmaf(f, p4.y, s4.y);
                s4.z = fmaf(f, p4.z, s4.z);
                s4.w = fmaf(f, p4.w, s4.w);
            }
            float inv = Linv[a];
            s4.x *= inv; s4.y *= inv; s4.z *= inv; s4.w *= inv;
            *(float4*)&AgV[(size_t)bh * (A_ * D_) + a * D_ + d4 * 4] = s4;
        }
    }
}

// ---------------- stage 2: query -> agents, softmax over A=40 ----------------
__global__ __launch_bounds__(256) void stage2(
    const float* __restrict__ Ql, const float* __restrict__ Ag,
    const float* __restrict__ AgV, const float* __restrict__ dist,
    float* __restrict__ Out)
{
    const int bx = blockIdx.x;
    const int bh = bx >> 3;
    const int b = bh / H_, h = bh % H_;
    const int s0 = (bx & 7) * 256;
    const int t = threadIdx.x;
    const int s = s0 + t;

    __shared__ float ag2[A_][D_];
    __shared__ float av[A_][D_];
    __shared__ float scl[256][41];

    for (int i = t; i < A_ * D_; i += 256) {
        ((float*)ag2)[i] = Ag[(size_t)bh * (A_ * D_) + i] * SCALE_;
        ((float*)av)[i]  = AgV[(size_t)bh * (A_ * D_) + i];
    }
    __syncthreads();

    const float* __restrict__ qrow = Ql + ((size_t)bh * S_ + s) * D_;
    float4 fq[16];
#pragma unroll
    for (int d4 = 0; d4 < 16; d4++) fq[d4] = *(const float4*)&qrow[d4 * 4];

    for (int a = 0; a < A_; a++) {
        const float* pe = dist + (size_t)(s - a + 2047) * D_;
        float sum = 0.0f;
#pragma unroll
        for (int d4 = 0; d4 < 16; d4++) {
            float4 pp = *(const float4*)&pe[d4 * 4];
            float4 aa = *(const float4*)&ag2[a][d4 * 4];
            float4 qq = fq[d4];
            sum = fmaf(qq.x, aa.x + pp.x, sum);
            sum = fmaf(qq.y, aa.y + pp.y, sum);
            sum = fmaf(qq.z, aa.z + pp.z, sum);
            sum = fmaf(qq.w, aa.w + pp.w, sum);
        }
        scl[t][a] = sum;
    }
    float mx = -INFINITY;
    for (int a = 0; a < A_; a++) mx = fmaxf(mx, scl[t][a]);
    float sum = 0.0f;
    for (int a = 0; a < A_; a++) {
        float p = __expf(scl[t][a] - mx);
        scl[t][a] = p;
        sum += p;
    }
    float inv = 1.0f / sum;

    float4 o[16];
#pragma unroll
    for (int d4 = 0; d4 < 16; d4++) o[d4] = make_float4(0.f, 0.f, 0.f, 0.f);
    for (int a = 0; a < A_; a++) {
        float p = scl[t][a] * inv;
#pragma unroll
        for (int d4 = 0; d4 < 16; d4++) {
            float4 vv = *(const float4*)&av[a][d4 * 4];
            o[d4].x = fmaf(p, vv.x, o[d4].x);
            o[d4].y = fmaf(p, vv.y, o[d4].y);
            o[d4].z = fmaf(p, vv.z, o[d4].z);
            o[d4].w = fmaf(p, vv.w, o[d4].w);
        }
    }
    float* orow = Out + ((size_t)b * S_ + s) * HID + h * D_;
#pragma unroll
    for (int d4 = 0; d4 < 16; d4++) *(float4*)&orow[d4 * 4] = o[d4];
}

extern "C" void kernel_launch(void* const* d_in, const int* in_sizes, int n_in,
                              void* d_out, int out_size, void* d_ws, size_t ws_size,
                              hipStream_t stream) {
    const float* hs   = (const float*)d_in[0];
    const float* mask = (const float*)d_in[1];
    const float* Wq   = (const float*)d_in[2];
    const float* bq   = (const float*)d_in[3];
    const float* Wk   = (const float*)d_in[4];
    const float* bk   = (const float*)d_in[5];
    const float* Wv   = (const float*)d_in[6];
    const float* bv   = (const float*)d_in[7];
    const float* dist = (const float*)d_in[8];
    float* out = (float*)d_out;

    float* ws = (float*)d_ws;
    const size_t QKV = (size_t)B_ * H_ * S_ * D_;   // 25,165,824 floats each
    const size_t AG  = (size_t)B_ * H_ * A_ * D_;   // 491,520 floats
    float* Q     = ws;
    float* K     = ws + QKV;
    float* V     = ws + 2 * QKV;
    float* Agent = ws + 3 * QKV;
    float* AgV   = Agent + AG;
    unsigned short* Wth = (unsigned short*)(AgV + AG);
    unsigned short* Wtl = Wth + (size_t)3 * HID * HID;
    float* Pacc = (float*)(Wtl + (size_t)3 * HID * HID);   // 192*8*40*64 = 3,932,160 fl
    float* Pm   = Pacc + (size_t)B_ * H_ * CH1 * A_ * D_;
    float* Pl   = Pm + (size_t)B_ * H_ * CH1 * A_;
    // total ws: ~330 MB

    wt_convert<<<(3 * 192 * 768 + 255) / 256, 256, 0, stream>>>(Wq, Wk, Wv, Wth, Wtl);
    dim3 gg(6, 3, 256);
    qkv_mfma<<<gg, 256, 0, stream>>>(hs, Wth, Wtl, bq, bk, bv, Q, K, V);
    agent_pool<<<(B_ * H_ * A_ * D_ + 255) / 256, 256, 0, stream>>>(Q, Agent);
    dim3 g1(CH1, B_ * H_);
    stage1_part<<<g1, 256, 0, stream>>>(K, V, Agent, dist, mask, Pacc, Pm, Pl);
    stage1_reduce<<<B_ * H_, 256, 0, stream>>>(Pacc, Pm, Pl, AgV);
    stage2<<<B_ * H_ * (S_ / 256), 256, 0, stream>>>(Q, Agent, AgV, dist, out);
}

// Round 4
// 740.889 us; speedup vs baseline: 3.9048x; 1.4198x over previous
//
#include <hip/hip_runtime.h>
#include <math.h>

#define B_ 16
#define S_ 2048
#define H_ 12
#define D_ 64
#define HID 768
#define A_ 40
#define SCALE_ 0.125f
#define CH1 8          // stage1 s-chunks per (b,h)
#define SUBT 64        // s per subtile
#define NSUB 4         // subtiles per block (256 s per block)
#define S2T 128        // stage2 s-tile per block

typedef __attribute__((ext_vector_type(8))) short short8v;   // 8 bf16 (4 VGPR)
typedef __attribute__((ext_vector_type(4))) float f32x4;     // MFMA C/D

__device__ __forceinline__ unsigned f2bf_bits(float x) {
    unsigned u = __float_as_uint(x);
    return (u + 0x7FFFu + ((u >> 16) & 1u)) >> 16;   // RTNE
}

// split 8 fp32 -> hi/lo bf16 packed as int4 (8 bf16 = 16B each)
__device__ __forceinline__ void split8(const float* x, int4& hi, int4& lo) {
    unsigned h[8], l[8];
#pragma unroll
    for (int i = 0; i < 8; i++) {
        unsigned hb = f2bf_bits(x[i]);
        float hf = __uint_as_float(hb << 16);
        unsigned lb = f2bf_bits(x[i] - hf);
        h[i] = hb; l[i] = lb;
    }
    hi = make_int4((int)(h[0] | (h[1] << 16)), (int)(h[2] | (h[3] << 16)),
                   (int)(h[4] | (h[5] << 16)), (int)(h[6] | (h[7] << 16)));
    lo = make_int4((int)(l[0] | (l[1] << 16)), (int)(l[2] | (l[3] << 16)),
                   (int)(l[4] | (l[5] << 16)), (int)(l[6] | (l[7] << 16)));
}

// ---------------- W transpose + bf16 hi/lo split: Wt[z][n][k] ----------------
__global__ void wt_convert(const float* __restrict__ Wq, const float* __restrict__ Wk,
                           const float* __restrict__ Wv,
                           unsigned short* __restrict__ Wth, unsigned short* __restrict__ Wtl)
{
    int idx = blockIdx.x * 256 + threadIdx.x;          // 3 * 192 * 768
    if (idx >= 3 * 192 * 768) return;
    int n  = idx % 768;
    int kc = (idx / 768) % 192;
    int z  = idx / (768 * 192);
    const float* W = (z == 0) ? Wq : (z == 1) ? Wk : Wv;
    unsigned short h4[4], l4[4];
#pragma unroll
    for (int i = 0; i < 4; i++) {
        float x = W[(size_t)(4 * kc + i) * HID + n];
        unsigned hb = f2bf_bits(x);
        float hf = __uint_as_float(hb << 16);
        h4[i] = (unsigned short)hb;
        l4[i] = (unsigned short)f2bf_bits(x - hf);
    }
    size_t o = ((size_t)z * HID + n) * HID + 4 * kc;
    *(ushort4*)&Wth[o] = make_ushort4(h4[0], h4[1], h4[2], h4[3]);
    *(ushort4*)&Wtl[o] = make_ushort4(l4[0], l4[1], l4[2], l4[3]);
}

// ---------------- QKV projection: bf16x3 MFMA GEMM, 128x128 tile, BK=32 ----------------
__global__ __launch_bounds__(256, 2) void qkv_mfma(
    const float* __restrict__ X,
    const unsigned short* __restrict__ Wth, const unsigned short* __restrict__ Wtl,
    const float* __restrict__ bq, const float* __restrict__ bk, const float* __restrict__ bv,
    float* __restrict__ Q, float* __restrict__ K, float* __restrict__ V)
{
    const int nt = blockIdx.x;        // 0..5
    const int zz = blockIdx.y;        // 0..2
    const int mt = blockIdx.z;        // 0..255
    const int m0 = mt * 128, n0 = nt * 128;

    const float* __restrict__ bias = (zz == 0) ? bq : (zz == 1) ? bk : bv;
    float* __restrict__ Out        = (zz == 0) ? Q  : (zz == 1) ? K  : V;
    const unsigned short* __restrict__ Bhg = Wth + (size_t)zz * HID * HID;
    const unsigned short* __restrict__ Blg = Wtl + (size_t)zz * HID * HID;

    __shared__ unsigned short Ah[128][40];
    __shared__ unsigned short Al[128][40];
    __shared__ unsigned short Bh[128][40];
    __shared__ unsigned short Bl[128][40];

    const int t = threadIdx.x;
    const int lane = t & 63, w = t >> 6;
    const int wm = (w >> 1) * 64, wn = (w & 1) * 64;
    const int fr = lane & 15, kc = lane >> 4;

    const int sr = t >> 1, sc = (t & 1) * 16;

    f32x4 acc[4][4];
#pragma unroll
    for (int i = 0; i < 4; i++)
#pragma unroll
        for (int j = 0; j < 4; j++) acc[i][j] = (f32x4){0.f, 0.f, 0.f, 0.f};

    for (int k0 = 0; k0 < HID; k0 += 32) {
        float xv[16];
        const float* xp = X + (size_t)(m0 + sr) * HID + k0 + sc;
#pragma unroll
        for (int q = 0; q < 4; q++) {
            float4 f = *(const float4*)(xp + 4 * q);
            xv[4 * q + 0] = f.x; xv[4 * q + 1] = f.y; xv[4 * q + 2] = f.z; xv[4 * q + 3] = f.w;
        }
        int4 ah0, al0, ah1, al1;
        split8(xv, ah0, al0);
        split8(xv + 8, ah1, al1);
        size_t bo = (size_t)(n0 + sr) * HID + k0 + sc;
        int4 bh0 = *(const int4*)&Bhg[bo];
        int4 bh1 = *(const int4*)&Bhg[bo + 8];
        int4 bl0 = *(const int4*)&Blg[bo];
        int4 bl1 = *(const int4*)&Blg[bo + 8];

        __syncthreads();
        *(int4*)&Ah[sr][sc]     = ah0;  *(int4*)&Ah[sr][sc + 8] = ah1;
        *(int4*)&Al[sr][sc]     = al0;  *(int4*)&Al[sr][sc + 8] = al1;
        *(int4*)&Bh[sr][sc]     = bh0;  *(int4*)&Bh[sr][sc + 8] = bh1;
        *(int4*)&Bl[sr][sc]     = bl0;  *(int4*)&Bl[sr][sc + 8] = bl1;
        __syncthreads();

        short8v a_h[4], a_l[4], b_h[4], b_l[4];
#pragma unroll
        for (int i = 0; i < 4; i++) {
            a_h[i] = *(const short8v*)&Ah[wm + i * 16 + fr][kc * 8];
            a_l[i] = *(const short8v*)&Al[wm + i * 16 + fr][kc * 8];
            b_h[i] = *(const short8v*)&Bh[wn + i * 16 + fr][kc * 8];
            b_l[i] = *(const short8v*)&Bl[wn + i * 16 + fr][kc * 8];
        }
#pragma unroll
        for (int i = 0; i < 4; i++)
#pragma unroll
            for (int j = 0; j < 4; j++) {
                acc[i][j] = __builtin_amdgcn_mfma_f32_16x16x32_bf16(a_h[i], b_h[j], acc[i][j], 0, 0, 0);
                acc[i][j] = __builtin_amdgcn_mfma_f32_16x16x32_bf16(a_l[i], b_h[j], acc[i][j], 0, 0, 0);
                acc[i][j] = __builtin_amdgcn_mfma_f32_16x16x32_bf16(a_h[i], b_l[j], acc[i][j], 0, 0, 0);
            }
    }

    const float scl = (zz == 1) ? SCALE_ : 1.0f;
#pragma unroll
    for (int j = 0; j < 4; j++) {
        int n = n0 + wn + j * 16 + fr;
        float bj = bias[n];
        int h = n >> 6, d = n & 63;
#pragma unroll
        for (int i = 0; i < 4; i++) {
            int mb = m0 + wm + i * 16 + kc * 4;
#pragma unroll
            for (int r = 0; r < 4; r++) {
                int m = mb + r;
                int b = m >> 11, s = m & 2047;
                Out[(((size_t)b * H_ + h) * S_ + s) * D_ + d] = (acc[i][j][r] + bj) * scl;
            }
        }
    }
}

// ---------------- agent pooling ----------------
__global__ void agent_pool(const float* __restrict__ Q, float* __restrict__ Ag)
{
    int idx = blockIdx.x * 256 + threadIdx.x;
    if (idx >= B_ * H_ * A_ * D_) return;
    int d  = idx & 63;
    int a  = (idx >> 6) % A_;
    int bh = idx / (A_ * D_);
    float src = ((float)a + 0.5f) * (2048.0f / 40.0f) - 0.5f;
    src = fminf(fmaxf(src, 0.0f), 2047.0f);
    int lo = (int)floorf(src);
    int hi = min(lo + 1, S_ - 1);
    float w = src - (float)lo;
    const float* base = Q + (size_t)bh * (S_ * D_);
    Ag[idx] = base[lo * D_ + d] * (1.0f - w) + base[hi * D_ + d] * w;
}

// ---------------- stage 1 partial: split-S flash, 4 online subtiles of 64 ----------------
__global__ __launch_bounds__(256, 3) void stage1_part(
    const float* __restrict__ Kl, const float* __restrict__ Vl,
    const float* __restrict__ Ag, const float* __restrict__ dist,
    const float* __restrict__ mask,
    float* __restrict__ Pacc, float* __restrict__ Pm, float* __restrict__ Pl)
{
    const int q  = blockIdx.x;       // 0..7
    const int bh = blockIdx.y;       // 0..191
    const int b  = bh / H_;
    const int s0 = q * (NSUB * SUBT);
    const float* __restrict__ kb = Kl + (size_t)bh * (S_ * D_);
    const float* __restrict__ vb = Vl + (size_t)bh * (S_ * D_);

    __shared__ float ag[A_][D_];
    __shared__ float pv[103 * 68];
    __shared__ float sc[SUBT][44];
    __shared__ float pm6[6][A_];
    __shared__ float mrow[A_], lrow[A_], resc[A_];

    const int t  = threadIdx.x;
    const int sl = t >> 2, dq = t & 3;

    for (int i = t; i < A_ * D_ / 4; i += 256)
        ((float4*)ag)[i] = ((const float4*)(Ag + (size_t)bh * (A_ * D_)))[i];
    if (t < A_) { mrow[t] = -INFINITY; lrow[t] = 0.0f; }

    float4 acc[3];
#pragma unroll
    for (int ii = 0; ii < 3; ii++) acc[ii] = make_float4(0.f, 0.f, 0.f, 0.f);

    for (int st = 0; st < NSUB; st++) {
        const int sb = s0 + st * SUBT;
        const int jbase = 1984 - sb;

        __syncthreads();
        for (int i = t; i < 103 * 16; i += 256) {
            int r = i >> 4, c = i & 15;
            *(float4*)&pv[r * 68 + c * 4] = *(const float4*)&dist[(size_t)(jbase + r) * D_ + c * 4];
        }
        const int s = sb + sl;
        float4 kreg[4];
        const float* kp = kb + (size_t)s * D_ + dq * 16;
#pragma unroll
        for (int c = 0; c < 4; c++) kreg[c] = *(const float4*)(kp + 4 * c);
        float mval = mask[(size_t)b * S_ + s];
        __syncthreads();

        for (int a = 0; a < A_; a++) {
            const float* per = &pv[(a + 63 - sl) * 68 + dq * 16];
            const float* agr = &ag[a][dq * 16];
            float sum = 0.0f;
#pragma unroll
            for (int c = 0; c < 4; c++) {
                float4 p4 = *(const float4*)(per + 4 * c);
                float4 a4 = *(const float4*)(agr + 4 * c);
                float4 k4 = kreg[c];
                sum = fmaf(a4.x, k4.x + p4.x, sum);
                sum = fmaf(a4.y, k4.y + p4.y, sum);
                sum = fmaf(a4.z, k4.z + p4.z, sum);
                sum = fmaf(a4.w, k4.w + p4.w, sum);
            }
            sum += __shfl_xor(sum, 1);
            sum += __shfl_xor(sum, 2);
            if (dq == 0) sc[sl][a] = sum + mval;
        }
        __syncthreads();

        for (int i = t; i < SUBT * 16; i += 256) {
            int r = i >> 4, c = i & 15;
            *(float4*)&pv[r * 68 + c * 4] = *(const float4*)&vb[(size_t)(sb + r) * D_ + c * 4];
        }
        if (t < 240) {
            int a = t % 40, r6 = t / 40;
            float mx = -INFINITY;
            for (int i = r6; i < SUBT; i += 6) mx = fmaxf(mx, sc[i][a]);
            pm6[r6][a] = mx;
        }
        __syncthreads();
        if (t < A_) {
            float lm = pm6[0][t];
#pragma unroll
            for (int r6 = 1; r6 < 6; r6++) lm = fmaxf(lm, pm6[r6][t]);
            float mnew = fmaxf(mrow[t], lm);
            resc[t] = __expf(mrow[t] - mnew);
            mrow[t] = mnew;
        }
        __syncthreads();
        for (int i = t; i < SUBT * A_; i += 256) {
            int rr = i / 40, aa = i - rr * 40;
            sc[rr][aa] = __expf(sc[rr][aa] - mrow[aa]);
        }
        __syncthreads();
        if (t < 240) {
            int a = t % 40, r6 = t / 40;
            float sm = 0.0f;
            for (int i = r6; i < SUBT; i += 6) sm += sc[i][a];
            pm6[r6][a] = sm;
        }
        __syncthreads();
        if (t < A_) {
            float ls = pm6[0][t] + pm6[1][t] + pm6[2][t] + pm6[3][t] + pm6[4][t] + pm6[5][t];
            lrow[t] = lrow[t] * resc[t] + ls;
        }

#pragma unroll
        for (int ii = 0; ii < 3; ii++) {
            int i = t + ii * 256;
            if (i < A_ * 16) {
                int a = i >> 4, d4 = i & 15;
                float rs = resc[a];
                float4 c4 = acc[ii];
                c4.x *= rs; c4.y *= rs; c4.z *= rs; c4.w *= rs;
                for (int rr = 0; rr < SUBT; rr++) {
                    float p = sc[rr][a];
                    float4 v4 = *(const float4*)&pv[rr * 68 + d4 * 4];
                    c4.x = fmaf(p, v4.x, c4.x);
                    c4.y = fmaf(p, v4.y, c4.y);
                    c4.z = fmaf(p, v4.z, c4.z);
                    c4.w = fmaf(p, v4.w, c4.w);
                }
                acc[ii] = c4;
            }
        }
    }
    __syncthreads();
#pragma unroll
    for (int ii = 0; ii < 3; ii++) {
        int i = t + ii * 256;
        if (i < A_ * 16) {
            int a = i >> 4, d4 = i & 15;
            *(float4*)&Pacc[(((size_t)(bh * CH1 + q) * A_) + a) * D_ + d4 * 4] = acc[ii];
        }
    }
    if (t < A_) {
        Pm[(size_t)(bh * CH1 + q) * A_ + t] = mrow[t];
        Pl[(size_t)(bh * CH1 + q) * A_ + t] = lrow[t];
    }
}

// ---------------- stage 1 reduce ----------------
__global__ __launch_bounds__(256) void stage1_reduce(
    const float* __restrict__ Pacc, const float* __restrict__ Pm,
    const float* __restrict__ Pl, float* __restrict__ AgV)
{
    const int bh = blockIdx.x;
    const int t = threadIdx.x;
    __shared__ float F[CH1][A_], Linv[A_];
    if (t < A_) {
        float M = -INFINITY;
#pragma unroll
        for (int q = 0; q < CH1; q++) M = fmaxf(M, Pm[(size_t)(bh * CH1 + q) * A_ + t]);
        float L = 0.0f;
#pragma unroll
        for (int q = 0; q < CH1; q++) {
            float f = __expf(Pm[(size_t)(bh * CH1 + q) * A_ + t] - M);
            F[q][t] = f;
            L = fmaf(f, Pl[(size_t)(bh * CH1 + q) * A_ + t], L);
        }
        Linv[t] = 1.0f / L;
    }
    __syncthreads();
#pragma unroll
    for (int ii = 0; ii < 3; ii++) {
        int i = t + ii * 256;
        if (i < A_ * 16) {
            int a = i >> 4, d4 = i & 15;
            float4 s4 = make_float4(0.f, 0.f, 0.f, 0.f);
            for (int q = 0; q < CH1; q++) {
                float f = F[q][a];
                float4 p4 = *(const float4*)&Pacc[(((size_t)(bh * CH1 + q) * A_) + a) * D_ + d4 * 4];
                s4.x = fmaf(f, p4.x, s4.x);
                s4.y = fmaf(f, p4.y, s4.y);
                s4.z = fmaf(f, p4.z, s4.z);
                s4.w = fmaf(f, p4.w, s4.w);
            }
            float inv = Linv[a];
            s4.x *= inv; s4.y *= inv; s4.z *= inv; s4.w *= inv;
            *(float4*)&AgV[(size_t)bh * (A_ * D_) + a * D_ + d4 * 4] = s4;
        }
    }
}

// ---------------- stage 2 v2: LDS dist-band, 128 s per block, 2 threads/s ----------------
// score2[s,a] = q[s,:]·(SCALE*agent[a,:] + dist[s-a+2047,:]); softmax over a; @ agent_v
__global__ __launch_bounds__(256, 2) void stage2(
    const float* __restrict__ Ql, const float* __restrict__ Ag,
    const float* __restrict__ AgV, const float* __restrict__ dist,
    float* __restrict__ Out)
{
    const int s0 = blockIdx.x * S2T;         // 0..15 chunks
    const int bh = blockIdx.y;               // 0..191
    const int b = bh / H_, h = bh % H_;
    const int t = threadIdx.x;
    const int sl = t >> 1;                   // 0..127 local s
    const int hf = t & 1;                    // d-half
    const int s  = s0 + sl;
    const int doff = hf * 32;

    __shared__ float band[167 * 68];         // dist rows jbase..jbase+166, stride 68 (2-way max)
    __shared__ float ag2[A_][68];            // SCALE * agent
    __shared__ float av[A_][68];

    // ---- stage band (coalesced, once) + ag2/av ----
    const int jbase = s0 + 2008;             // s - a + 2047 for s=s0+[0,128), a=[0,40)
    for (int i = t; i < 167 * 16; i += 256) {
        int r = i >> 4, c = i & 15;
        *(float4*)&band[r * 68 + c * 4] = *(const float4*)&dist[(size_t)(jbase + r) * D_ + c * 4];
    }
    for (int i = t; i < A_ * 16; i += 256) {
        int r = i >> 4, c = i & 15;
        float4 g = *(const float4*)&Ag[(size_t)bh * (A_ * D_) + r * D_ + c * 4];
        g.x *= SCALE_; g.y *= SCALE_; g.z *= SCALE_; g.w *= SCALE_;
        *(float4*)&ag2[r][c * 4] = g;
        *(float4*)&av[r][c * 4] = *(const float4*)&AgV[(size_t)bh * (A_ * D_) + r * D_ + c * 4];
    }

    // per-thread q half-row (8 float4 = 32 VGPR)
    const float* __restrict__ qrow = Ql + ((size_t)bh * S_ + s) * D_ + doff;
    float4 fq[8];
#pragma unroll
    for (int c = 0; c < 8; c++) fq[c] = *(const float4*)&qrow[c * 4];
    __syncthreads();

    // ---- scores: band row r = sl + 39 - a ----
    float sc[A_];
#pragma unroll
    for (int a = 0; a < A_; a++) {
        const float* pe = &band[(sl + 39 - a) * 68 + doff];
        const float* ar = &ag2[a][doff];
        float sum = 0.0f;
#pragma unroll
        for (int c = 0; c < 8; c++) {
            float4 p4 = *(const float4*)&pe[c * 4];
            float4 a4 = *(const float4*)&ar[c * 4];
            float4 q4 = fq[c];
            sum = fmaf(q4.x, a4.x + p4.x, sum);
            sum = fmaf(q4.y, a4.y + p4.y, sum);
            sum = fmaf(q4.z, a4.z + p4.z, sum);
            sum = fmaf(q4.w, a4.w + p4.w, sum);
        }
        sum += __shfl_xor(sum, 1);           // combine d-halves (paired lanes)
        sc[a] = sum;
    }

    // ---- softmax over 40 agents (both paired lanes compute identically) ----
    float mx = -INFINITY;
#pragma unroll
    for (int a = 0; a < A_; a++) mx = fmaxf(mx, sc[a]);
    float sum = 0.0f;
#pragma unroll
    for (int a = 0; a < A_; a++) {
        float p = __expf(sc[a] - mx);
        sc[a] = p;
        sum += p;
    }
    float inv = 1.0f / sum;

    // ---- PV: o[half] = sum_a p[a] * av[a][half] (av reads broadcast per half) ----
    float4 o[8];
#pragma unroll
    for (int c = 0; c < 8; c++) o[c] = make_float4(0.f, 0.f, 0.f, 0.f);
#pragma unroll
    for (int a = 0; a < A_; a++) {
        float p = sc[a] * inv;
        const float* vr = &av[a][doff];
#pragma unroll
        for (int c = 0; c < 8; c++) {
            float4 vv = *(const float4*)&vr[c * 4];
            o[c].x = fmaf(p, vv.x, o[c].x);
            o[c].y = fmaf(p, vv.y, o[c].y);
            o[c].z = fmaf(p, vv.z, o[c].z);
            o[c].w = fmaf(p, vv.w, o[c].w);
        }
    }
    float* orow = Out + ((size_t)b * S_ + s) * HID + h * D_ + doff;
#pragma unroll
    for (int c = 0; c < 8; c++) *(float4*)&orow[c * 4] = o[c];
}

extern "C" void kernel_launch(void* const* d_in, const int* in_sizes, int n_in,
                              void* d_out, int out_size, void* d_ws, size_t ws_size,
                              hipStream_t stream) {
    const float* hs   = (const float*)d_in[0];
    const float* mask = (const float*)d_in[1];
    const float* Wq   = (const float*)d_in[2];
    const float* bq   = (const float*)d_in[3];
    const float* Wk   = (const float*)d_in[4];
    const float* bk   = (const float*)d_in[5];
    const float* Wv   = (const float*)d_in[6];
    const float* bv   = (const float*)d_in[7];
    const float* dist = (const float*)d_in[8];
    float* out = (float*)d_out;

    float* ws = (float*)d_ws;
    const size_t QKV = (size_t)B_ * H_ * S_ * D_;
    const size_t AG  = (size_t)B_ * H_ * A_ * D_;
    float* Q     = ws;
    float* K     = ws + QKV;
    float* V     = ws + 2 * QKV;
    float* Agent = ws + 3 * QKV;
    float* AgV   = Agent + AG;
    unsigned short* Wth = (unsigned short*)(AgV + AG);
    unsigned short* Wtl = Wth + (size_t)3 * HID * HID;
    float* Pacc = (float*)(Wtl + (size_t)3 * HID * HID);
    float* Pm   = Pacc + (size_t)B_ * H_ * CH1 * A_ * D_;
    float* Pl   = Pm + (size_t)B_ * H_ * CH1 * A_;

    wt_convert<<<(3 * 192 * 768 + 255) / 256, 256, 0, stream>>>(Wq, Wk, Wv, Wth, Wtl);
    dim3 gg(6, 3, 256);
    qkv_mfma<<<gg, 256, 0, stream>>>(hs, Wth, Wtl, bq, bk, bv, Q, K, V);
    agent_pool<<<(B_ * H_ * A_ * D_ + 255) / 256, 256, 0, stream>>>(Q, Agent);
    dim3 g1(CH1, B_ * H_);
    stage1_part<<<g1, 256, 0, stream>>>(K, V, Agent, dist, mask, Pacc, Pm, Pl);
    stage1_reduce<<<B_ * H_, 256, 0, stream>>>(Pacc, Pm, Pl, AgV);
    dim3 g2(S_ / S2T, B_ * H_);
    stage2<<<g2, 256, 0, stream>>>(Q, Agent, AgV, dist, out);
}

// Round 5
// 739.273 us; speedup vs baseline: 3.9133x; 1.0022x over previous
//
#include <hip/hip_runtime.h>
#include <math.h>

#define B_ 16
#define S_ 2048
#define H_ 12
#define D_ 64
#define HID 768
#define A_ 40
#define SCALE_ 0.125f
#define CH1 8          // stage1 s-chunks per (b,h)
#define SUBT 64        // s per subtile
#define NSUB 4         // subtiles per block (256 s per block)
#define S2T 128        // stage2 s-tile per block

typedef __attribute__((ext_vector_type(8))) short short8v;   // 8 bf16 (4 VGPR)
typedef __attribute__((ext_vector_type(4))) float f32x4;     // MFMA C/D

__device__ __forceinline__ unsigned f2bf_bits(float x) {
    unsigned u = __float_as_uint(x);
    return (u + 0x7FFFu + ((u >> 16) & 1u)) >> 16;   // RTNE
}

// split 8 fp32 -> hi/lo bf16 packed as int4 (8 bf16 = 16B each)
__device__ __forceinline__ void split8(const float* x, int4& hi, int4& lo) {
    unsigned h[8], l[8];
#pragma unroll
    for (int i = 0; i < 8; i++) {
        unsigned hb = f2bf_bits(x[i]);
        float hf = __uint_as_float(hb << 16);
        unsigned lb = f2bf_bits(x[i] - hf);
        h[i] = hb; l[i] = lb;
    }
    hi = make_int4((int)(h[0] | (h[1] << 16)), (int)(h[2] | (h[3] << 16)),
                   (int)(h[4] | (h[5] << 16)), (int)(h[6] | (h[7] << 16)));
    lo = make_int4((int)(l[0] | (l[1] << 16)), (int)(l[2] | (l[3] << 16)),
                   (int)(l[4] | (l[5] << 16)), (int)(l[6] | (l[7] << 16)));
}

// ================= FAST PATH (fragment-major, no-LDS GEMM) =================

// X [32768][768] fp32 -> XhF/XlF fragment-major bf16:
// granule g = ((p*24 + kt)*8 + sub)*64 + lane; row = p*128+sub*16+(lane&15),
// cols = kt*32+(lane>>4)*8 .. +8. 16B granules, contiguous writes.
__global__ __launch_bounds__(256) void x_convert(
    const float* __restrict__ X,
    unsigned short* __restrict__ XhF, unsigned short* __restrict__ XlF)
{
    int g = blockIdx.x * 256 + threadIdx.x;          // 3,145,728 granules
    int lane = g & 63;
    int rest = g >> 6;
    int sub = rest & 7;
    int rest2 = rest >> 3;          // p*24 + kt
    int kt = rest2 % 24;
    int p  = rest2 / 24;
    int row  = p * 128 + sub * 16 + (lane & 15);
    int col0 = kt * 32 + (lane >> 4) * 8;
    float xv[8];
    const float* xp = X + (size_t)row * HID + col0;
    float4 f0 = *(const float4*)xp;
    float4 f1 = *(const float4*)(xp + 4);
    xv[0]=f0.x; xv[1]=f0.y; xv[2]=f0.z; xv[3]=f0.w;
    xv[4]=f1.x; xv[5]=f1.y; xv[6]=f1.z; xv[7]=f1.w;
    int4 hi, lo;
    split8(xv, hi, lo);
    *(int4*)&XhF[(size_t)g * 8] = hi;
    *(int4*)&XlF[(size_t)g * 8] = lo;
}

// W (3x [k][n] fp32) -> WhF/WlF fragment-major bf16 (transposed to [n][k] tiles):
// granule g = (((z*6+nt)*24 + kt)*8 + sub)*64 + lane; n = nt*128+sub*16+(lane&15),
// k = kt*32+(lane>>4)*8 .. +8
__global__ __launch_bounds__(256) void wtf_convert(
    const float* __restrict__ Wq, const float* __restrict__ Wk, const float* __restrict__ Wv,
    unsigned short* __restrict__ WhF, unsigned short* __restrict__ WlF)
{
    int g = blockIdx.x * 256 + threadIdx.x;          // 221,184 granules
    if (g >= 3 * 6 * 24 * 8 * 64) return;
    int lane = g & 63;
    int rest = g >> 6;
    int sub = rest & 7;
    int rest2 = rest >> 3;          // (z*6+nt)*24 + kt
    int kt = rest2 % 24;
    int rest3 = rest2 / 24;
    int nt = rest3 % 6;
    int z  = rest3 / 6;
    const float* W = (z == 0) ? Wq : (z == 1) ? Wk : Wv;
    int n  = nt * 128 + sub * 16 + (lane & 15);
    int k0 = kt * 32 + (lane >> 4) * 8;
    float xv[8];
#pragma unroll
    for (int j = 0; j < 8; j++) xv[j] = W[(size_t)(k0 + j) * HID + n];
    int4 hi, lo;
    split8(xv, hi, lo);
    *(int4*)&WhF[(size_t)g * 8] = hi;
    *(int4*)&WlF[(size_t)g * 8] = lo;
}

// Fragment-direct bf16x3 GEMM: no LDS, no barriers. 128x128 per block, 4 waves.
__global__ __launch_bounds__(256, 2) void qkv_fd(
    const unsigned short* __restrict__ XhF, const unsigned short* __restrict__ XlF,
    const unsigned short* __restrict__ WhF, const unsigned short* __restrict__ WlF,
    const float* __restrict__ bq, const float* __restrict__ bk, const float* __restrict__ bv,
    float* __restrict__ Q, float* __restrict__ K, float* __restrict__ V)
{
    const int mt = blockIdx.x;        // 0..255
    const int ny = blockIdx.y;        // 0..17  (z*6 + nt)
    const int z  = ny / 6, nt = ny % 6;
    const int n0 = nt * 128;

    const float* __restrict__ bias = (z == 0) ? bq : (z == 1) ? bk : bv;
    float* __restrict__ Out        = (z == 0) ? Q  : (z == 1) ? K  : V;

    const int t = threadIdx.x;
    const int lane = t & 63, w = t >> 6;
    const int wm = (w >> 1) * 64, wn = (w & 1) * 64;
    const int fr = lane & 15, kc = lane >> 4;
    const int subA = (w >> 1) * 4;    // + i
    const int subB = (w & 1) * 4;     // + j

    // granule pointers (16B units)
    const short8v* Ah = (const short8v*)XhF + (size_t)mt * 24 * 8 * 64;
    const short8v* Al = (const short8v*)XlF + (size_t)mt * 24 * 8 * 64;
    const short8v* Bh = (const short8v*)WhF + (size_t)ny * 24 * 8 * 64;
    const short8v* Bl = (const short8v*)WlF + (size_t)ny * 24 * 8 * 64;

    f32x4 acc[4][4];
#pragma unroll
    for (int i = 0; i < 4; i++)
#pragma unroll
        for (int j = 0; j < 4; j++) acc[i][j] = (f32x4){0.f, 0.f, 0.f, 0.f};

#pragma unroll 2
    for (int kt = 0; kt < 24; kt++) {
        const int oa = (kt * 8 + subA) * 64 + lane;
        const int ob = (kt * 8 + subB) * 64 + lane;
        short8v a_h[4], a_l[4], b_h[4], b_l[4];
#pragma unroll
        for (int i = 0; i < 4; i++) {
            a_h[i] = Ah[oa + i * 64];
            a_l[i] = Al[oa + i * 64];
            b_h[i] = Bh[ob + i * 64];
            b_l[i] = Bl[ob + i * 64];
        }
#pragma unroll
        for (int i = 0; i < 4; i++)
#pragma unroll
            for (int j = 0; j < 4; j++) {
                acc[i][j] = __builtin_amdgcn_mfma_f32_16x16x32_bf16(a_h[i], b_h[j], acc[i][j], 0, 0, 0);
                acc[i][j] = __builtin_amdgcn_mfma_f32_16x16x32_bf16(a_l[i], b_h[j], acc[i][j], 0, 0, 0);
                acc[i][j] = __builtin_amdgcn_mfma_f32_16x16x32_bf16(a_h[i], b_l[j], acc[i][j], 0, 0, 0);
            }
    }

    const float scl = (z == 1) ? SCALE_ : 1.0f;
#pragma unroll
    for (int j = 0; j < 4; j++) {
        int n = n0 + wn + j * 16 + fr;
        float bj = bias[n];
        int h = n >> 6, d = n & 63;
#pragma unroll
        for (int i = 0; i < 4; i++) {
            int mb = mt * 128 + wm + i * 16 + kc * 4;
#pragma unroll
            for (int r = 0; r < 4; r++) {
                int m = mb + r;
                int b = m >> 11, s = m & 2047;
                Out[(((size_t)b * H_ + h) * S_ + s) * D_ + d] = (acc[i][j][r] + bj) * scl;
            }
        }
    }
}

// ================= FALLBACK PATH (round-4 GEMM, in-kernel convert) =================

__global__ void wt_convert(const float* __restrict__ Wq, const float* __restrict__ Wk,
                           const float* __restrict__ Wv,
                           unsigned short* __restrict__ Wth, unsigned short* __restrict__ Wtl)
{
    int idx = blockIdx.x * 256 + threadIdx.x;          // 3 * 192 * 768
    if (idx >= 3 * 192 * 768) return;
    int n  = idx % 768;
    int kc = (idx / 768) % 192;
    int z  = idx / (768 * 192);
    const float* W = (z == 0) ? Wq : (z == 1) ? Wk : Wv;
    unsigned short h4[4], l4[4];
#pragma unroll
    for (int i = 0; i < 4; i++) {
        float x = W[(size_t)(4 * kc + i) * HID + n];
        unsigned hb = f2bf_bits(x);
        float hf = __uint_as_float(hb << 16);
        h4[i] = (unsigned short)hb;
        l4[i] = (unsigned short)f2bf_bits(x - hf);
    }
    size_t o = ((size_t)z * HID + n) * HID + 4 * kc;
    *(ushort4*)&Wth[o] = make_ushort4(h4[0], h4[1], h4[2], h4[3]);
    *(ushort4*)&Wtl[o] = make_ushort4(l4[0], l4[1], l4[2], l4[3]);
}

__global__ __launch_bounds__(256, 2) void qkv_mfma(
    const float* __restrict__ X,
    const unsigned short* __restrict__ Wth, const unsigned short* __restrict__ Wtl,
    const float* __restrict__ bq, const float* __restrict__ bk, const float* __restrict__ bv,
    float* __restrict__ Q, float* __restrict__ K, float* __restrict__ V)
{
    const int nt = blockIdx.x;
    const int zz = blockIdx.y;
    const int mt = blockIdx.z;
    const int m0 = mt * 128, n0 = nt * 128;

    const float* __restrict__ bias = (zz == 0) ? bq : (zz == 1) ? bk : bv;
    float* __restrict__ Out        = (zz == 0) ? Q  : (zz == 1) ? K  : V;
    const unsigned short* __restrict__ Bhg = Wth + (size_t)zz * HID * HID;
    const unsigned short* __restrict__ Blg = Wtl + (size_t)zz * HID * HID;

    __shared__ unsigned short Ah[128][40];
    __shared__ unsigned short Al[128][40];
    __shared__ unsigned short Bh[128][40];
    __shared__ unsigned short Bl[128][40];

    const int t = threadIdx.x;
    const int lane = t & 63, w = t >> 6;
    const int wm = (w >> 1) * 64, wn = (w & 1) * 64;
    const int fr = lane & 15, kc = lane >> 4;

    const int sr = t >> 1, sc = (t & 1) * 16;

    f32x4 acc[4][4];
#pragma unroll
    for (int i = 0; i < 4; i++)
#pragma unroll
        for (int j = 0; j < 4; j++) acc[i][j] = (f32x4){0.f, 0.f, 0.f, 0.f};

    for (int k0 = 0; k0 < HID; k0 += 32) {
        float xv[16];
        const float* xp = X + (size_t)(m0 + sr) * HID + k0 + sc;
#pragma unroll
        for (int q = 0; q < 4; q++) {
            float4 f = *(const float4*)(xp + 4 * q);
            xv[4 * q + 0] = f.x; xv[4 * q + 1] = f.y; xv[4 * q + 2] = f.z; xv[4 * q + 3] = f.w;
        }
        int4 ah0, al0, ah1, al1;
        split8(xv, ah0, al0);
        split8(xv + 8, ah1, al1);
        size_t bo = (size_t)(n0 + sr) * HID + k0 + sc;
        int4 bh0 = *(const int4*)&Bhg[bo];
        int4 bh1 = *(const int4*)&Bhg[bo + 8];
        int4 bl0 = *(const int4*)&Blg[bo];
        int4 bl1 = *(const int4*)&Blg[bo + 8];

        __syncthreads();
        *(int4*)&Ah[sr][sc]     = ah0;  *(int4*)&Ah[sr][sc + 8] = ah1;
        *(int4*)&Al[sr][sc]     = al0;  *(int4*)&Al[sr][sc + 8] = al1;
        *(int4*)&Bh[sr][sc]     = bh0;  *(int4*)&Bh[sr][sc + 8] = bh1;
        *(int4*)&Bl[sr][sc]     = bl0;  *(int4*)&Bl[sr][sc + 8] = bl1;
        __syncthreads();

        short8v a_h[4], a_l[4], b_h[4], b_l[4];
#pragma unroll
        for (int i = 0; i < 4; i++) {
            a_h[i] = *(const short8v*)&Ah[wm + i * 16 + fr][kc * 8];
            a_l[i] = *(const short8v*)&Al[wm + i * 16 + fr][kc * 8];
            b_h[i] = *(const short8v*)&Bh[wn + i * 16 + fr][kc * 8];
            b_l[i] = *(const short8v*)&Bl[wn + i * 16 + fr][kc * 8];
        }
#pragma unroll
        for (int i = 0; i < 4; i++)
#pragma unroll
            for (int j = 0; j < 4; j++) {
                acc[i][j] = __builtin_amdgcn_mfma_f32_16x16x32_bf16(a_h[i], b_h[j], acc[i][j], 0, 0, 0);
                acc[i][j] = __builtin_amdgcn_mfma_f32_16x16x32_bf16(a_l[i], b_h[j], acc[i][j], 0, 0, 0);
                acc[i][j] = __builtin_amdgcn_mfma_f32_16x16x32_bf16(a_h[i], b_l[j], acc[i][j], 0, 0, 0);
            }
    }

    const float scl = (zz == 1) ? SCALE_ : 1.0f;
#pragma unroll
    for (int j = 0; j < 4; j++) {
        int n = n0 + wn + j * 16 + fr;
        float bj = bias[n];
        int h = n >> 6, d = n & 63;
#pragma unroll
        for (int i = 0; i < 4; i++) {
            int mb = m0 + wm + i * 16 + kc * 4;
#pragma unroll
            for (int r = 0; r < 4; r++) {
                int m = mb + r;
                int b = m >> 11, s = m & 2047;
                Out[(((size_t)b * H_ + h) * S_ + s) * D_ + d] = (acc[i][j][r] + bj) * scl;
            }
        }
    }
}

// ================= SHARED: pooling, stage1, stage2 =================

__global__ void agent_pool(const float* __restrict__ Q, float* __restrict__ Ag)
{
    int idx = blockIdx.x * 256 + threadIdx.x;
    if (idx >= B_ * H_ * A_ * D_) return;
    int d  = idx & 63;
    int a  = (idx >> 6) % A_;
    int bh = idx / (A_ * D_);
    float src = ((float)a + 0.5f) * (2048.0f / 40.0f) - 0.5f;
    src = fminf(fmaxf(src, 0.0f), 2047.0f);
    int lo = (int)floorf(src);
    int hi = min(lo + 1, S_ - 1);
    float w = src - (float)lo;
    const float* base = Q + (size_t)bh * (S_ * D_);
    Ag[idx] = base[lo * D_ + d] * (1.0f - w) + base[hi * D_ + d] * w;
}

__global__ __launch_bounds__(256, 3) void stage1_part(
    const float* __restrict__ Kl, const float* __restrict__ Vl,
    const float* __restrict__ Ag, const float* __restrict__ dist,
    const float* __restrict__ mask,
    float* __restrict__ Pacc, float* __restrict__ Pm, float* __restrict__ Pl)
{
    const int q  = blockIdx.x;
    const int bh = blockIdx.y;
    const int b  = bh / H_;
    const int s0 = q * (NSUB * SUBT);
    const float* __restrict__ kb = Kl + (size_t)bh * (S_ * D_);
    const float* __restrict__ vb = Vl + (size_t)bh * (S_ * D_);

    __shared__ float ag[A_][D_];
    __shared__ float pv[103 * 68];
    __shared__ float sc[SUBT][44];
    __shared__ float pm6[6][A_];
    __shared__ float mrow[A_], lrow[A_], resc[A_];

    const int t  = threadIdx.x;
    const int sl = t >> 2, dq = t & 3;

    for (int i = t; i < A_ * D_ / 4; i += 256)
        ((float4*)ag)[i] = ((const float4*)(Ag + (size_t)bh * (A_ * D_)))[i];
    if (t < A_) { mrow[t] = -INFINITY; lrow[t] = 0.0f; }

    float4 acc[3];
#pragma unroll
    for (int ii = 0; ii < 3; ii++) acc[ii] = make_float4(0.f, 0.f, 0.f, 0.f);

    for (int st = 0; st < NSUB; st++) {
        const int sb = s0 + st * SUBT;
        const int jbase = 1984 - sb;

        __syncthreads();
        for (int i = t; i < 103 * 16; i += 256) {
            int r = i >> 4, c = i & 15;
            *(float4*)&pv[r * 68 + c * 4] = *(const float4*)&dist[(size_t)(jbase + r) * D_ + c * 4];
        }
        const int s = sb + sl;
        float4 kreg[4];
        const float* kp = kb + (size_t)s * D_ + dq * 16;
#pragma unroll
        for (int c = 0; c < 4; c++) kreg[c] = *(const float4*)(kp + 4 * c);
        float mval = mask[(size_t)b * S_ + s];
        __syncthreads();

        for (int a = 0; a < A_; a++) {
            const float* per = &pv[(a + 63 - sl) * 68 + dq * 16];
            const float* agr = &ag[a][dq * 16];
            float sum = 0.0f;
#pragma unroll
            for (int c = 0; c < 4; c++) {
                float4 p4 = *(const float4*)(per + 4 * c);
                float4 a4 = *(const float4*)(agr + 4 * c);
                float4 k4 = kreg[c];
                sum = fmaf(a4.x, k4.x + p4.x, sum);
                sum = fmaf(a4.y, k4.y + p4.y, sum);
                sum = fmaf(a4.z, k4.z + p4.z, sum);
                sum = fmaf(a4.w, k4.w + p4.w, sum);
            }
            sum += __shfl_xor(sum, 1);
            sum += __shfl_xor(sum, 2);
            if (dq == 0) sc[sl][a] = sum + mval;
        }
        __syncthreads();

        for (int i = t; i < SUBT * 16; i += 256) {
            int r = i >> 4, c = i & 15;
            *(float4*)&pv[r * 68 + c * 4] = *(const float4*)&vb[(size_t)(sb + r) * D_ + c * 4];
        }
        if (t < 240) {
            int a = t % 40, r6 = t / 40;
            float mx = -INFINITY;
            for (int i = r6; i < SUBT; i += 6) mx = fmaxf(mx, sc[i][a]);
            pm6[r6][a] = mx;
        }
        __syncthreads();
        if (t < A_) {
            float lm = pm6[0][t];
#pragma unroll
            for (int r6 = 1; r6 < 6; r6++) lm = fmaxf(lm, pm6[r6][t]);
            float mnew = fmaxf(mrow[t], lm);
            resc[t] = __expf(mrow[t] - mnew);
            mrow[t] = mnew;
        }
        __syncthreads();
        for (int i = t; i < SUBT * A_; i += 256) {
            int rr = i / 40, aa = i - rr * 40;
            sc[rr][aa] = __expf(sc[rr][aa] - mrow[aa]);
        }
        __syncthreads();
        if (t < 240) {
            int a = t % 40, r6 = t / 40;
            float sm = 0.0f;
            for (int i = r6; i < SUBT; i += 6) sm += sc[i][a];
            pm6[r6][a] = sm;
        }
        __syncthreads();
        if (t < A_) {
            float ls = pm6[0][t] + pm6[1][t] + pm6[2][t] + pm6[3][t] + pm6[4][t] + pm6[5][t];
            lrow[t] = lrow[t] * resc[t] + ls;
        }

#pragma unroll
        for (int ii = 0; ii < 3; ii++) {
            int i = t + ii * 256;
            if (i < A_ * 16) {
                int a = i >> 4, d4 = i & 15;
                float rs = resc[a];
                float4 c4 = acc[ii];
                c4.x *= rs; c4.y *= rs; c4.z *= rs; c4.w *= rs;
                for (int rr = 0; rr < SUBT; rr++) {
                    float p = sc[rr][a];
                    float4 v4 = *(const float4*)&pv[rr * 68 + d4 * 4];
                    c4.x = fmaf(p, v4.x, c4.x);
                    c4.y = fmaf(p, v4.y, c4.y);
                    c4.z = fmaf(p, v4.z, c4.z);
                    c4.w = fmaf(p, v4.w, c4.w);
                }
                acc[ii] = c4;
            }
        }
    }
    __syncthreads();
#pragma unroll
    for (int ii = 0; ii < 3; ii++) {
        int i = t + ii * 256;
        if (i < A_ * 16) {
            int a = i >> 4, d4 = i & 15;
            *(float4*)&Pacc[(((size_t)(bh * CH1 + q) * A_) + a) * D_ + d4 * 4] = acc[ii];
        }
    }
    if (t < A_) {
        Pm[(size_t)(bh * CH1 + q) * A_ + t] = mrow[t];
        Pl[(size_t)(bh * CH1 + q) * A_ + t] = lrow[t];
    }
}

__global__ __launch_bounds__(256) void stage1_reduce(
    const float* __restrict__ Pacc, const float* __restrict__ Pm,
    const float* __restrict__ Pl, float* __restrict__ AgV)
{
    const int bh = blockIdx.x;
    const int t = threadIdx.x;
    __shared__ float F[CH1][A_], Linv[A_];
    if (t < A_) {
        float M = -INFINITY;
#pragma unroll
        for (int q = 0; q < CH1; q++) M = fmaxf(M, Pm[(size_t)(bh * CH1 + q) * A_ + t]);
        float L = 0.0f;
#pragma unroll
        for (int q = 0; q < CH1; q++) {
            float f = __expf(Pm[(size_t)(bh * CH1 + q) * A_ + t] - M);
            F[q][t] = f;
            L = fmaf(f, Pl[(size_t)(bh * CH1 + q) * A_ + t], L);
        }
        Linv[t] = 1.0f / L;
    }
    __syncthreads();
#pragma unroll
    for (int ii = 0; ii < 3; ii++) {
        int i = t + ii * 256;
        if (i < A_ * 16) {
            int a = i >> 4, d4 = i & 15;
            float4 s4 = make_float4(0.f, 0.f, 0.f, 0.f);
            for (int q = 0; q < CH1; q++) {
                float f = F[q][a];
                float4 p4 = *(const float4*)&Pacc[(((size_t)(bh * CH1 + q) * A_) + a) * D_ + d4 * 4];
                s4.x = fmaf(f, p4.x, s4.x);
                s4.y = fmaf(f, p4.y, s4.y);
                s4.z = fmaf(f, p4.z, s4.z);
                s4.w = fmaf(f, p4.w, s4.w);
            }
            float inv = Linv[a];
            s4.x *= inv; s4.y *= inv; s4.z *= inv; s4.w *= inv;
            *(float4*)&AgV[(size_t)bh * (A_ * D_) + a * D_ + d4 * 4] = s4;
        }
    }
}

__global__ __launch_bounds__(256, 2) void stage2(
    const float* __restrict__ Ql, const float* __restrict__ Ag,
    const float* __restrict__ AgV, const float* __restrict__ dist,
    float* __restrict__ Out)
{
    const int s0 = blockIdx.x * S2T;
    const int bh = blockIdx.y;
    const int b = bh / H_, h = bh % H_;
    const int t = threadIdx.x;
    const int sl = t >> 1;
    const int hf = t & 1;
    const int s  = s0 + sl;
    const int doff = hf * 32;

    __shared__ float band[167 * 68];
    __shared__ float ag2[A_][68];
    __shared__ float av[A_][68];

    const int jbase = s0 + 2008;
    for (int i = t; i < 167 * 16; i += 256) {
        int r = i >> 4, c = i & 15;
        *(float4*)&band[r * 68 + c * 4] = *(const float4*)&dist[(size_t)(jbase + r) * D_ + c * 4];
    }
    for (int i = t; i < A_ * 16; i += 256) {
        int r = i >> 4, c = i & 15;
        float4 g = *(const float4*)&Ag[(size_t)bh * (A_ * D_) + r * D_ + c * 4];
        g.x *= SCALE_; g.y *= SCALE_; g.z *= SCALE_; g.w *= SCALE_;
        *(float4*)&ag2[r][c * 4] = g;
        *(float4*)&av[r][c * 4] = *(const float4*)&AgV[(size_t)bh * (A_ * D_) + r * D_ + c * 4];
    }

    const float* __restrict__ qrow = Ql + ((size_t)bh * S_ + s) * D_ + doff;
    float4 fq[8];
#pragma unroll
    for (int c = 0; c < 8; c++) fq[c] = *(const float4*)&qrow[c * 4];
    __syncthreads();

    float sc[A_];
#pragma unroll
    for (int a = 0; a < A_; a++) {
        const float* pe = &band[(sl + 39 - a) * 68 + doff];
        const float* ar = &ag2[a][doff];
        float sum = 0.0f;
#pragma unroll
        for (int c = 0; c < 8; c++) {
            float4 p4 = *(const float4*)&pe[c * 4];
            float4 a4 = *(const float4*)&ar[c * 4];
            float4 q4 = fq[c];
            sum = fmaf(q4.x, a4.x + p4.x, sum);
            sum = fmaf(q4.y, a4.y + p4.y, sum);
            sum = fmaf(q4.z, a4.z + p4.z, sum);
            sum = fmaf(q4.w, a4.w + p4.w, sum);
        }
        sum += __shfl_xor(sum, 1);
        sc[a] = sum;
    }

    float mx = -INFINITY;
#pragma unroll
    for (int a = 0; a < A_; a++) mx = fmaxf(mx, sc[a]);
    float sum = 0.0f;
#pragma unroll
    for (int a = 0; a < A_; a++) {
        float p = __expf(sc[a] - mx);
        sc[a] = p;
        sum += p;
    }
    float inv = 1.0f / sum;

    float4 o[8];
#pragma unroll
    for (int c = 0; c < 8; c++) o[c] = make_float4(0.f, 0.f, 0.f, 0.f);
#pragma unroll
    for (int a = 0; a < A_; a++) {
        float p = sc[a] * inv;
        const float* vr = &av[a][doff];
#pragma unroll
        for (int c = 0; c < 8; c++) {
            float4 vv = *(const float4*)&vr[c * 4];
            o[c].x = fmaf(p, vv.x, o[c].x);
            o[c].y = fmaf(p, vv.y, o[c].y);
            o[c].z = fmaf(p, vv.z, o[c].z);
            o[c].w = fmaf(p, vv.w, o[c].w);
        }
    }
    float* orow = Out + ((size_t)b * S_ + s) * HID + h * D_ + doff;
#pragma unroll
    for (int c = 0; c < 8; c++) *(float4*)&orow[c * 4] = o[c];
}

extern "C" void kernel_launch(void* const* d_in, const int* in_sizes, int n_in,
                              void* d_out, int out_size, void* d_ws, size_t ws_size,
                              hipStream_t stream) {
    const float* hs   = (const float*)d_in[0];
    const float* mask = (const float*)d_in[1];
    const float* Wq   = (const float*)d_in[2];
    const float* bq   = (const float*)d_in[3];
    const float* Wk   = (const float*)d_in[4];
    const float* bk   = (const float*)d_in[5];
    const float* Wv   = (const float*)d_in[6];
    const float* bv   = (const float*)d_in[7];
    const float* dist = (const float*)d_in[8];
    float* out = (float*)d_out;

    float* ws = (float*)d_ws;
    const size_t QKV = (size_t)B_ * H_ * S_ * D_;   // 25,165,824 floats each
    const size_t AG  = (size_t)B_ * H_ * A_ * D_;   // 491,520 floats
    float* Q     = ws;
    float* K     = ws + QKV;
    float* V     = ws + 2 * QKV;
    float* Agent = ws + 3 * QKV;
    float* AgV   = Agent + AG;
    float* Pacc  = AgV + AG;                        // 3,932,160 floats
    float* Pm    = Pacc + (size_t)B_ * H_ * CH1 * A_ * D_;
    float* Pl    = Pm + (size_t)B_ * H_ * CH1 * A_;
    unsigned short* tail = (unsigned short*)(Pl + (size_t)B_ * H_ * CH1 * A_);

    // fast path needs: tail holds XhF+XlF (2x 25,165,824 us) + WhF+WlF (2x 1,769,472 us)
    const size_t FAST_NEED = ((size_t)(3 * QKV + 2 * AG) + 3932160 + 2 * 61440) * 4
                           + ((size_t)2 * 25165824 + 2 * 1769472) * 2;

    if (ws_size >= FAST_NEED) {
        unsigned short* XhF = tail;
        unsigned short* XlF = XhF + (size_t)25165824;
        unsigned short* WhF = XlF + (size_t)25165824;
        unsigned short* WlF = WhF + (size_t)1769472;

        x_convert<<<12288, 256, 0, stream>>>(hs, XhF, XlF);
        wtf_convert<<<864, 256, 0, stream>>>(Wq, Wk, Wv, WhF, WlF);
        dim3 gg(256, 18);
        qkv_fd<<<gg, 256, 0, stream>>>(XhF, XlF, WhF, WlF, bq, bk, bv, Q, K, V);
    } else {
        unsigned short* Wth = tail;
        unsigned short* Wtl = Wth + (size_t)3 * HID * HID;
        wt_convert<<<(3 * 192 * 768 + 255) / 256, 256, 0, stream>>>(Wq, Wk, Wv, Wth, Wtl);
        dim3 gg(6, 3, 256);
        qkv_mfma<<<gg, 256, 0, stream>>>(hs, Wth, Wtl, bq, bk, bv, Q, K, V);
    }

    agent_pool<<<(B_ * H_ * A_ * D_ + 255) / 256, 256, 0, stream>>>(Q, Agent);
    dim3 g1(CH1, B_ * H_);
    stage1_part<<<g1, 256, 0, stream>>>(K, V, Agent, dist, mask, Pacc, Pm, Pl);
    stage1_reduce<<<B_ * H_, 256, 0, stream>>>(Pacc, Pm, Pl, AgV);
    dim3 g2(S_ / S2T, B_ * H_);
    stage2<<<g2, 256, 0, stream>>>(Q, Agent, AgV, dist, out);
}

// Round 6
// 698.804 us; speedup vs baseline: 4.1400x; 1.0579x over previous
//
#include <hip/hip_runtime.h>
#include <math.h>

#define B_ 16
#define S_ 2048
#define H_ 12
#define D_ 64
#define HID 768
#define A_ 40
#define SCALE_ 0.125f
#define CH1 8          // stage1 s-chunks per (b,h)
#define SUBT 64        // s per subtile
#define NSUB 4         // subtiles per block (256 s per block)
#define S2T 128        // stage2 s-tile per block

typedef __attribute__((ext_vector_type(8))) short short8v;   // 8 bf16 (4 VGPR)
typedef __attribute__((ext_vector_type(4))) float f32x4;     // MFMA C/D

__device__ __forceinline__ unsigned f2bf_bits(float x) {
    unsigned u = __float_as_uint(x);
    return (u + 0x7FFFu + ((u >> 16) & 1u)) >> 16;   // RTNE
}

// split 8 fp32 -> hi/lo bf16 via native __bf16 casts (RTNE; compiler emits cvt_pk)
__device__ __forceinline__ void split8c(const float* x, int4& hi, int4& lo) {
    unsigned h[8], l[8];
#pragma unroll
    for (int i = 0; i < 8; i++) {
        __bf16 bh = (__bf16)x[i];
        float hf = (float)bh;
        __bf16 bl = (__bf16)(x[i] - hf);
        h[i] = (unsigned)__builtin_bit_cast(unsigned short, bh);
        l[i] = (unsigned)__builtin_bit_cast(unsigned short, bl);
    }
    hi = make_int4((int)(h[0] | (h[1] << 16)), (int)(h[2] | (h[3] << 16)),
                   (int)(h[4] | (h[5] << 16)), (int)(h[6] | (h[7] << 16)));
    lo = make_int4((int)(l[0] | (l[1] << 16)), (int)(l[2] | (l[3] << 16)),
                   (int)(l[4] | (l[5] << 16)), (int)(l[6] | (l[7] << 16)));
}

// ---------------- W transpose + bf16 hi/lo split: Wt[z][n][k] ----------------
__global__ void wt_convert(const float* __restrict__ Wq, const float* __restrict__ Wk,
                           const float* __restrict__ Wv,
                           unsigned short* __restrict__ Wth, unsigned short* __restrict__ Wtl)
{
    int idx = blockIdx.x * 256 + threadIdx.x;          // 3 * 192 * 768
    if (idx >= 3 * 192 * 768) return;
    int n  = idx % 768;
    int kc = (idx / 768) % 192;
    int z  = idx / (768 * 192);
    const float* W = (z == 0) ? Wq : (z == 1) ? Wk : Wv;
    unsigned short h4[4], l4[4];
#pragma unroll
    for (int i = 0; i < 4; i++) {
        float x = W[(size_t)(4 * kc + i) * HID + n];
        unsigned hb = f2bf_bits(x);
        float hf = __uint_as_float(hb << 16);
        h4[i] = (unsigned short)hb;
        l4[i] = (unsigned short)f2bf_bits(x - hf);
    }
    size_t o = ((size_t)z * HID + n) * HID + 4 * kc;
    *(ushort4*)&Wth[o] = make_ushort4(h4[0], h4[1], h4[2], h4[3]);
    *(ushort4*)&Wtl[o] = make_ushort4(l4[0], l4[1], l4[2], l4[3]);
}

// ---------------- QKV projection: bf16x3 MFMA GEMM, 128x256 tile, 512 thr ----------------
// Block = 128 m-rows x 256 n-cols for one z. 8 waves of 64x64. X converted in-kernel
// (9x redundancy vs 18x before), W pre-split. K output pre-scaled by SCALE.
__global__ __launch_bounds__(512, 2) void qkv_z(
    const float* __restrict__ X,
    const unsigned short* __restrict__ Wth, const unsigned short* __restrict__ Wtl,
    const float* __restrict__ bq, const float* __restrict__ bk, const float* __restrict__ bv,
    float* __restrict__ Q, float* __restrict__ K, float* __restrict__ V)
{
    const int nt = blockIdx.x;        // 0..2  (n0 = nt*256)
    const int zz = blockIdx.y;        // 0..2
    const int mt = blockIdx.z;        // 0..255
    const int m0 = mt * 128, n0 = nt * 256;

    const float* __restrict__ bias = (zz == 0) ? bq : (zz == 1) ? bk : bv;
    float* __restrict__ Out        = (zz == 0) ? Q  : (zz == 1) ? K  : V;
    const unsigned short* __restrict__ Bhg = Wth + (size_t)zz * HID * HID;
    const unsigned short* __restrict__ Blg = Wtl + (size_t)zz * HID * HID;

    __shared__ unsigned short Ah[128][40];   // pad-40 rows (80B): near-conflict-free
    __shared__ unsigned short Al[128][40];
    __shared__ unsigned short Bh[256][40];
    __shared__ unsigned short Bl[256][40];

    const int t = threadIdx.x;
    const int lane = t & 63, w = t >> 6;
    const int wm = (w & 1) * 64, wn = (w >> 1) * 64;   // 2 m-waves x 4 n-waves
    const int fr = lane & 15, kc = lane >> 4;

    const int sr = t >> 2, sca = (t & 3) * 8;    // A staging: 128 rows x 4 chunks of 8
    const int sb = t >> 1, scb = (t & 1) * 16;   // B staging: 256 rows x 2 chunks of 16

    f32x4 acc[4][4];
#pragma unroll
    for (int i = 0; i < 4; i++)
#pragma unroll
        for (int j = 0; j < 4; j++) acc[i][j] = (f32x4){0.f, 0.f, 0.f, 0.f};

    for (int k0 = 0; k0 < HID; k0 += 32) {
        // ---- global -> reg (+convert A) ----
        float xv[8];
        const float* xp = X + (size_t)(m0 + sr) * HID + k0 + sca;
        float4 f0 = *(const float4*)xp;
        float4 f1 = *(const float4*)(xp + 4);
        xv[0] = f0.x; xv[1] = f0.y; xv[2] = f0.z; xv[3] = f0.w;
        xv[4] = f1.x; xv[5] = f1.y; xv[6] = f1.z; xv[7] = f1.w;
        int4 ah, al;
        split8c(xv, ah, al);
        size_t bo = (size_t)(n0 + sb) * HID + k0 + scb;
        int4 bh0 = *(const int4*)&Bhg[bo];
        int4 bh1 = *(const int4*)&Bhg[bo + 8];
        int4 bl0 = *(const int4*)&Blg[bo];
        int4 bl1 = *(const int4*)&Blg[bo + 8];

        __syncthreads();   // prior tile's LDS reads complete
        *(int4*)&Ah[sr][sca] = ah;
        *(int4*)&Al[sr][sca] = al;
        *(int4*)&Bh[sb][scb]     = bh0;  *(int4*)&Bh[sb][scb + 8] = bh1;
        *(int4*)&Bl[sb][scb]     = bl0;  *(int4*)&Bl[sb][scb + 8] = bl1;
        __syncthreads();

        // ---- fragments + MFMA ----
        short8v a_h[4], a_l[4], b_h[4], b_l[4];
#pragma unroll
        for (int i = 0; i < 4; i++) {
            a_h[i] = *(const short8v*)&Ah[wm + i * 16 + fr][kc * 8];
            a_l[i] = *(const short8v*)&Al[wm + i * 16 + fr][kc * 8];
            b_h[i] = *(const short8v*)&Bh[wn + i * 16 + fr][kc * 8];
            b_l[i] = *(const short8v*)&Bl[wn + i * 16 + fr][kc * 8];
        }
#pragma unroll
        for (int i = 0; i < 4; i++)
#pragma unroll
            for (int j = 0; j < 4; j++) {
                acc[i][j] = __builtin_amdgcn_mfma_f32_16x16x32_bf16(a_h[i], b_h[j], acc[i][j], 0, 0, 0);
                acc[i][j] = __builtin_amdgcn_mfma_f32_16x16x32_bf16(a_l[i], b_h[j], acc[i][j], 0, 0, 0);
                acc[i][j] = __builtin_amdgcn_mfma_f32_16x16x32_bf16(a_h[i], b_l[j], acc[i][j], 0, 0, 0);
            }
    }

    // ---- epilogue: bias, optional SCALE (K), write [b,h,s,d] ----
    const float scl = (zz == 1) ? SCALE_ : 1.0f;
#pragma unroll
    for (int j = 0; j < 4; j++) {
        int n = n0 + wn + j * 16 + fr;
        float bj = bias[n];
        int h = n >> 6, d = n & 63;
#pragma unroll
        for (int i = 0; i < 4; i++) {
            int mb = m0 + wm + i * 16 + kc * 4;
#pragma unroll
            for (int r = 0; r < 4; r++) {
                int m = mb + r;
                int b = m >> 11, s = m & 2047;
                Out[(((size_t)b * H_ + h) * S_ + s) * D_ + d] = (acc[i][j][r] + bj) * scl;
            }
        }
    }
}

// ---------------- agent pooling ----------------
__global__ void agent_pool(const float* __restrict__ Q, float* __restrict__ Ag)
{
    int idx = blockIdx.x * 256 + threadIdx.x;
    if (idx >= B_ * H_ * A_ * D_) return;
    int d  = idx & 63;
    int a  = (idx >> 6) % A_;
    int bh = idx / (A_ * D_);
    float src = ((float)a + 0.5f) * (2048.0f / 40.0f) - 0.5f;
    src = fminf(fmaxf(src, 0.0f), 2047.0f);
    int lo = (int)floorf(src);
    int hi = min(lo + 1, S_ - 1);
    float w = src - (float)lo;
    const float* base = Q + (size_t)bh * (S_ * D_);
    Ag[idx] = base[lo * D_ + d] * (1.0f - w) + base[hi * D_ + d] * w;
}

// ---------------- stage 1 partial: split-S flash, 4 online subtiles of 64 ----------------
__global__ __launch_bounds__(256, 3) void stage1_part(
    const float* __restrict__ Kl, const float* __restrict__ Vl,
    const float* __restrict__ Ag, const float* __restrict__ dist,
    const float* __restrict__ mask,
    float* __restrict__ Pacc, float* __restrict__ Pm, float* __restrict__ Pl)
{
    const int q  = blockIdx.x;
    const int bh = blockIdx.y;
    const int b  = bh / H_;
    const int s0 = q * (NSUB * SUBT);
    const float* __restrict__ kb = Kl + (size_t)bh * (S_ * D_);
    const float* __restrict__ vb = Vl + (size_t)bh * (S_ * D_);

    __shared__ float ag[A_][D_];
    __shared__ float pv[103 * 68];
    __shared__ float sc[SUBT][44];
    __shared__ float pm6[6][A_];
    __shared__ float mrow[A_], lrow[A_], resc[A_];

    const int t  = threadIdx.x;
    const int sl = t >> 2, dq = t & 3;

    for (int i = t; i < A_ * D_ / 4; i += 256)
        ((float4*)ag)[i] = ((const float4*)(Ag + (size_t)bh * (A_ * D_)))[i];
    if (t < A_) { mrow[t] = -INFINITY; lrow[t] = 0.0f; }

    float4 acc[3];
#pragma unroll
    for (int ii = 0; ii < 3; ii++) acc[ii] = make_float4(0.f, 0.f, 0.f, 0.f);

    for (int st = 0; st < NSUB; st++) {
        const int sb = s0 + st * SUBT;
        const int jbase = 1984 - sb;

        __syncthreads();
        for (int i = t; i < 103 * 16; i += 256) {
            int r = i >> 4, c = i & 15;
            *(float4*)&pv[r * 68 + c * 4] = *(const float4*)&dist[(size_t)(jbase + r) * D_ + c * 4];
        }
        const int s = sb + sl;
        float4 kreg[4];
        const float* kp = kb + (size_t)s * D_ + dq * 16;
#pragma unroll
        for (int c = 0; c < 4; c++) kreg[c] = *(const float4*)(kp + 4 * c);
        float mval = mask[(size_t)b * S_ + s];
        __syncthreads();

        for (int a = 0; a < A_; a++) {
            const float* per = &pv[(a + 63 - sl) * 68 + dq * 16];
            const float* agr = &ag[a][dq * 16];
            float sum = 0.0f;
#pragma unroll
            for (int c = 0; c < 4; c++) {
                float4 p4 = *(const float4*)(per + 4 * c);
                float4 a4 = *(const float4*)(agr + 4 * c);
                float4 k4 = kreg[c];
                sum = fmaf(a4.x, k4.x + p4.x, sum);
                sum = fmaf(a4.y, k4.y + p4.y, sum);
                sum = fmaf(a4.z, k4.z + p4.z, sum);
                sum = fmaf(a4.w, k4.w + p4.w, sum);
            }
            sum += __shfl_xor(sum, 1);
            sum += __shfl_xor(sum, 2);
            if (dq == 0) sc[sl][a] = sum + mval;
        }
        __syncthreads();

        for (int i = t; i < SUBT * 16; i += 256) {
            int r = i >> 4, c = i & 15;
            *(float4*)&pv[r * 68 + c * 4] = *(const float4*)&vb[(size_t)(sb + r) * D_ + c * 4];
        }
        if (t < 240) {
            int a = t % 40, r6 = t / 40;
            float mx = -INFINITY;
            for (int i = r6; i < SUBT; i += 6) mx = fmaxf(mx, sc[i][a]);
            pm6[r6][a] = mx;
        }
        __syncthreads();
        if (t < A_) {
            float lm = pm6[0][t];
#pragma unroll
            for (int r6 = 1; r6 < 6; r6++) lm = fmaxf(lm, pm6[r6][t]);
            float mnew = fmaxf(mrow[t], lm);
            resc[t] = __expf(mrow[t] - mnew);
            mrow[t] = mnew;
        }
        __syncthreads();
        for (int i = t; i < SUBT * A_; i += 256) {
            int rr = i / 40, aa = i - rr * 40;
            sc[rr][aa] = __expf(sc[rr][aa] - mrow[aa]);
        }
        __syncthreads();
        if (t < 240) {
            int a = t % 40, r6 = t / 40;
            float sm = 0.0f;
            for (int i = r6; i < SUBT; i += 6) sm += sc[i][a];
            pm6[r6][a] = sm;
        }
        __syncthreads();
        if (t < A_) {
            float ls = pm6[0][t] + pm6[1][t] + pm6[2][t] + pm6[3][t] + pm6[4][t] + pm6[5][t];
            lrow[t] = lrow[t] * resc[t] + ls;
        }

#pragma unroll
        for (int ii = 0; ii < 3; ii++) {
            int i = t + ii * 256;
            if (i < A_ * 16) {
                int a = i >> 4, d4 = i & 15;
                float rs = resc[a];
                float4 c4 = acc[ii];
                c4.x *= rs; c4.y *= rs; c4.z *= rs; c4.w *= rs;
                for (int rr = 0; rr < SUBT; rr++) {
                    float p = sc[rr][a];
                    float4 v4 = *(const float4*)&pv[rr * 68 + d4 * 4];
                    c4.x = fmaf(p, v4.x, c4.x);
                    c4.y = fmaf(p, v4.y, c4.y);
                    c4.z = fmaf(p, v4.z, c4.z);
                    c4.w = fmaf(p, v4.w, c4.w);
                }
                acc[ii] = c4;
            }
        }
    }
    __syncthreads();
#pragma unroll
    for (int ii = 0; ii < 3; ii++) {
        int i = t + ii * 256;
        if (i < A_ * 16) {
            int a = i >> 4, d4 = i & 15;
            *(float4*)&Pacc[(((size_t)(bh * CH1 + q) * A_) + a) * D_ + d4 * 4] = acc[ii];
        }
    }
    if (t < A_) {
        Pm[(size_t)(bh * CH1 + q) * A_ + t] = mrow[t];
        Pl[(size_t)(bh * CH1 + q) * A_ + t] = lrow[t];
    }
}

// ---------------- stage 1 reduce ----------------
__global__ __launch_bounds__(256) void stage1_reduce(
    const float* __restrict__ Pacc, const float* __restrict__ Pm,
    const float* __restrict__ Pl, float* __restrict__ AgV)
{
    const int bh = blockIdx.x;
    const int t = threadIdx.x;
    __shared__ float F[CH1][A_], Linv[A_];
    if (t < A_) {
        float M = -INFINITY;
#pragma unroll
        for (int q = 0; q < CH1; q++) M = fmaxf(M, Pm[(size_t)(bh * CH1 + q) * A_ + t]);
        float L = 0.0f;
#pragma unroll
        for (int q = 0; q < CH1; q++) {
            float f = __expf(Pm[(size_t)(bh * CH1 + q) * A_ + t] - M);
            F[q][t] = f;
            L = fmaf(f, Pl[(size_t)(bh * CH1 + q) * A_ + t], L);
        }
        Linv[t] = 1.0f / L;
    }
    __syncthreads();
#pragma unroll
    for (int ii = 0; ii < 3; ii++) {
        int i = t + ii * 256;
        if (i < A_ * 16) {
            int a = i >> 4, d4 = i & 15;
            float4 s4 = make_float4(0.f, 0.f, 0.f, 0.f);
            for (int q = 0; q < CH1; q++) {
                float f = F[q][a];
                float4 p4 = *(const float4*)&Pacc[(((size_t)(bh * CH1 + q) * A_) + a) * D_ + d4 * 4];
                s4.x = fmaf(f, p4.x, s4.x);
                s4.y = fmaf(f, p4.y, s4.y);
                s4.z = fmaf(f, p4.z, s4.z);
                s4.w = fmaf(f, p4.w, s4.w);
            }
            float inv = Linv[a];
            s4.x *= inv; s4.y *= inv; s4.z *= inv; s4.w *= inv;
            *(float4*)&AgV[(size_t)bh * (A_ * D_) + a * D_ + d4 * 4] = s4;
        }
    }
}

// ---------------- stage 2: LDS dist-band, 128 s per block, 2 threads/s ----------------
__global__ __launch_bounds__(256, 2) void stage2(
    const float* __restrict__ Ql, const float* __restrict__ Ag,
    const float* __restrict__ AgV, const float* __restrict__ dist,
    float* __restrict__ Out)
{
    const int s0 = blockIdx.x * S2T;
    const int bh = blockIdx.y;
    const int b = bh / H_, h = bh % H_;
    const int t = threadIdx.x;
    const int sl = t >> 1;
    const int hf = t & 1;
    const int s  = s0 + sl;
    const int doff = hf * 32;

    __shared__ float band[167 * 68];
    __shared__ float ag2[A_][68];
    __shared__ float av[A_][68];

    const int jbase = s0 + 2008;
    for (int i = t; i < 167 * 16; i += 256) {
        int r = i >> 4, c = i & 15;
        *(float4*)&band[r * 68 + c * 4] = *(const float4*)&dist[(size_t)(jbase + r) * D_ + c * 4];
    }
    for (int i = t; i < A_ * 16; i += 256) {
        int r = i >> 4, c = i & 15;
        float4 g = *(const float4*)&Ag[(size_t)bh * (A_ * D_) + r * D_ + c * 4];
        g.x *= SCALE_; g.y *= SCALE_; g.z *= SCALE_; g.w *= SCALE_;
        *(float4*)&ag2[r][c * 4] = g;
        *(float4*)&av[r][c * 4] = *(const float4*)&AgV[(size_t)bh * (A_ * D_) + r * D_ + c * 4];
    }

    const float* __restrict__ qrow = Ql + ((size_t)bh * S_ + s) * D_ + doff;
    float4 fq[8];
#pragma unroll
    for (int c = 0; c < 8; c++) fq[c] = *(const float4*)&qrow[c * 4];
    __syncthreads();

    float sc[A_];
#pragma unroll
    for (int a = 0; a < A_; a++) {
        const float* pe = &band[(sl + 39 - a) * 68 + doff];
        const float* ar = &ag2[a][doff];
        float sum = 0.0f;
#pragma unroll
        for (int c = 0; c < 8; c++) {
            float4 p4 = *(const float4*)&pe[c * 4];
            float4 a4 = *(const float4*)&ar[c * 4];
            float4 q4 = fq[c];
            sum = fmaf(q4.x, a4.x + p4.x, sum);
            sum = fmaf(q4.y, a4.y + p4.y, sum);
            sum = fmaf(q4.z, a4.z + p4.z, sum);
            sum = fmaf(q4.w, a4.w + p4.w, sum);
        }
        sum += __shfl_xor(sum, 1);
        sc[a] = sum;
    }

    float mx = -INFINITY;
#pragma unroll
    for (int a = 0; a < A_; a++) mx = fmaxf(mx, sc[a]);
    float sum = 0.0f;
#pragma unroll
    for (int a = 0; a < A_; a++) {
        float p = __expf(sc[a] - mx);
        sc[a] = p;
        sum += p;
    }
    float inv = 1.0f / sum;

    float4 o[8];
#pragma unroll
    for (int c = 0; c < 8; c++) o[c] = make_float4(0.f, 0.f, 0.f, 0.f);
#pragma unroll
    for (int a = 0; a < A_; a++) {
        float p = sc[a] * inv;
        const float* vr = &av[a][doff];
#pragma unroll
        for (int c = 0; c < 8; c++) {
            float4 vv = *(const float4*)&vr[c * 4];
            o[c].x = fmaf(p, vv.x, o[c].x);
            o[c].y = fmaf(p, vv.y, o[c].y);
            o[c].z = fmaf(p, vv.z, o[c].z);
            o[c].w = fmaf(p, vv.w, o[c].w);
        }
    }
    float* orow = Out + ((size_t)b * S_ + s) * HID + h * D_ + doff;
#pragma unroll
    for (int c = 0; c < 8; c++) *(float4*)&orow[c * 4] = o[c];
}

extern "C" void kernel_launch(void* const* d_in, const int* in_sizes, int n_in,
                              void* d_out, int out_size, void* d_ws, size_t ws_size,
                              hipStream_t stream) {
    const float* hs   = (const float*)d_in[0];
    const float* mask = (const float*)d_in[1];
    const float* Wq   = (const float*)d_in[2];
    const float* bq   = (const float*)d_in[3];
    const float* Wk   = (const float*)d_in[4];
    const float* bk   = (const float*)d_in[5];
    const float* Wv   = (const float*)d_in[6];
    const float* bv   = (const float*)d_in[7];
    const float* dist = (const float*)d_in[8];
    float* out = (float*)d_out;

    float* ws = (float*)d_ws;
    const size_t QKV = (size_t)B_ * H_ * S_ * D_;   // 25,165,824 floats each
    const size_t AG  = (size_t)B_ * H_ * A_ * D_;   // 491,520 floats
    float* Q     = ws;
    float* K     = ws + QKV;
    float* V     = ws + 2 * QKV;
    float* Agent = ws + 3 * QKV;
    float* AgV   = Agent + AG;
    float* Pacc  = AgV + AG;
    float* Pm    = Pacc + (size_t)B_ * H_ * CH1 * A_ * D_;
    float* Pl    = Pm + (size_t)B_ * H_ * CH1 * A_;
    unsigned short* Wth = (unsigned short*)(Pl + (size_t)B_ * H_ * CH1 * A_);
    unsigned short* Wtl = Wth + (size_t)3 * HID * HID;
    // total ws: ~329 MB (same as proven round-4 layout)

    wt_convert<<<(3 * 192 * 768 + 255) / 256, 256, 0, stream>>>(Wq, Wk, Wv, Wth, Wtl);
    dim3 gg(3, 3, 256);
    qkv_z<<<gg, 512, 0, stream>>>(hs, Wth, Wtl, bq, bk, bv, Q, K, V);
    agent_pool<<<(B_ * H_ * A_ * D_ + 255) / 256, 256, 0, stream>>>(Q, Agent);
    dim3 g1(CH1, B_ * H_);
    stage1_part<<<g1, 256, 0, stream>>>(K, V, Agent, dist, mask, Pacc, Pm, Pl);
    stage1_reduce<<<B_ * H_, 256, 0, stream>>>(Pacc, Pm, Pl, AgV);
    dim3 g2(S_ / S2T, B_ * H_);
    stage2<<<g2, 256, 0, stream>>>(Q, Agent, AgV, dist, out);
}